// Round 9
// baseline (713.784 us; speedup 1.0000x reference)
//
#include <hip/hip_runtime.h>
#include <hip/hip_bf16.h>
#include <math.h>

#define Nn 4
#define Cc 64
#define Hh 192
#define Ww 192
#define HW (Hh*Ww)          // 36864
#define PIXBLK 144          // HW/256

typedef __attribute__((ext_vector_type(4))) float f32x4;
typedef __attribute__((ext_vector_type(8))) short s16x8;

struct __align__(8) US4 { unsigned short x,y,z,w; };

static __device__ __forceinline__ unsigned short f2bf(float v){
    __hip_bfloat16 b = __float2bfloat16(v);
    return *(unsigned short*)&b;
}
static __device__ __forceinline__ float bf2f(unsigned int u){
    return __uint_as_float(u<<16);
}

// ---------------- kernel 0: x -> bf16 pixel-major [n][px][64] ----------------
__global__ void k_xprep(const float* __restrict__ x, unsigned short* __restrict__ xbf){
    int bid = blockIdx.x;              // Nn*144
    int n = bid/144, chunk = bid%144;
    int px = chunk*256 + threadIdx.x;
    const float* xb = x + (size_t)n*Cc*HW + px;
    unsigned int pk[32];
    #pragma unroll
    for(int c2=0;c2<32;c2++){
        float f0 = xb[(size_t)(2*c2)*HW];
        float f1 = xb[(size_t)(2*c2+1)*HW];
        pk[c2] = (unsigned int)f2bf(f0) | ((unsigned int)f2bf(f1)<<16);
    }
    uint4* dst = (uint4*)(xbf + ((size_t)n*HW + px)*64);
    #pragma unroll
    for(int q=0;q<8;q++){
        uint4 v; v.x=pk[q*4]; v.y=pk[q*4+1]; v.z=pk[q*4+2]; v.w=pk[q*4+3];
        dst[q] = v;
    }
}

// ---------------- kernel 1: weight prep (240 blocks) + global average pool (256 blocks) ----------------
// g_wt LINEAR layout: ((og*9+t)*16+o)*64 + c   (read direct to regs in conv3m)
// fu1/fu2 swizzled for LDS: o*128 + (c ^ ((o&15)<<3))
__global__ void k_prep(const float* __restrict__ hw, const float* __restrict__ fw1,
                       const float* __restrict__ fw2, const float* __restrict__ x,
                       unsigned short* __restrict__ g_wt,
                       unsigned short* __restrict__ g_wfu1,
                       unsigned short* __restrict__ g_wfu2,
                       float* __restrict__ fp){
    int b = blockIdx.x;
    __shared__ float sm[4];
    if(b < 240){
        int idx = b*256 + threadIdx.x;    // 0..61439
        if(idx<36864){
            int og = idx/9216, r = idx%9216;
            int t = r/1024, r2 = r%1024;
            int o = r2>>6, c = r2&63;
            g_wt[idx] = f2bf(hw[(size_t)(((og*16+o)*64)+c)*9 + t]);
        } else if(idx<53248){
            int i = idx-36864;
            int o = i>>7, c = i&127;
            g_wfu1[o*128 + (c ^ ((o&15)<<3))] = f2bf(fw1[i]);
        } else {
            int i = idx-53248;
            int o = i>>7, c = i&127;
            g_wfu2[o*128 + (c ^ ((o&15)<<3))] = f2bf(fw2[i]);
        }
    } else {
        int nc = b-240;                    // 0..255
        const float4* p = (const float4*)(x + (size_t)nc*HW);
        float s = 0.f;
        for(int i=threadIdx.x;i<HW/4;i+=256){ float4 v=p[i]; s += v.x+v.y+v.z+v.w; }
        for(int o=32;o>0;o>>=1) s += __shfl_down(s,o);
        int wid = threadIdx.x>>6, ln = threadIdx.x&63;
        if(ln==0) sm[wid]=s;
        __syncthreads();
        if(threadIdx.x==0) fp[nc] = (sm[0]+sm[1]+sm[2]+sm[3]) / (float)HW;
    }
}

// ---------------- kernel 2: dynamic filter (matvec + GN + softmax) ----------------
__global__ void k_filter(const float* __restrict__ fp, const float* __restrict__ wf,
                         const float* __restrict__ gg, const float* __restrict__ gb,
                         float* __restrict__ fsm){
    int n = blockIdx.x;
    __shared__ float sfp[64];
    __shared__ float sfw[576];
    __shared__ float gstat[8];
    int t = threadIdx.x;                       // 0..575
    if(t<64) sfp[t] = fp[n*64+t];
    __syncthreads();
    const float* wr = wf + (size_t)t*64;
    float acc = 0.f;
    #pragma unroll 8
    for(int k=0;k<64;k++) acc += sfp[k]*wr[k];
    sfw[t] = acc;
    __syncthreads();
    if(t<4){
        float s=0.f,s2=0.f;
        for(int i=0;i<144;i++){ float v=sfw[t*144+i]; s+=v; s2+=v*v; }
        float m = s/144.f;
        gstat[t*2]   = m;
        gstat[t*2+1] = s2/144.f - m*m;
    }
    __syncthreads();
    int g = t/144;
    float m = gstat[g*2], var = gstat[g*2+1];
    float z = (acc-m)*rsqrtf(var+1e-5f)*gg[t] + gb[t];
    sfw[t] = z;
    __syncthreads();
    if(t<64){
        float mx = -1e30f;
        for(int j=0;j<9;j++) mx = fmaxf(mx, sfw[t*9+j]);
        float e[9]; float se=0.f;
        for(int j=0;j<9;j++){ e[j]=expf(sfw[t*9+j]-mx); se+=e[j]; }
        float inv = 1.f/se;
        for(int j=0;j<9;j++) fsm[((size_t)n*64+t)*9+j] = e[j]*inv;
    }
}

// ---------------- kernel 3: low/high + conv1x1(64->16)+PReLU + high GN partials ----------------
// 32x8 tiles, 1 px/thread, 576 blocks; input = xbf pixel-major bf16 (1 line/px).
#define HBS 72
__global__ void __launch_bounds__(256,2)
k_lowhigh(const unsigned short* __restrict__ xbf, const float* __restrict__ fsm,
          const float* __restrict__ w1, const float* __restrict__ b1,
          const float* __restrict__ a1p,
          unsigned short* __restrict__ high, float* __restrict__ y1,
          float* __restrict__ partial){
    int bid = blockIdx.x;
    int n = bid/144, tile = bid%144;
    int h0 = (tile/6)*8, w0 = (tile%6)*32;
    int t = threadIdx.x;
    int r0 = t>>5, wl = t&31;
    __shared__ __align__(16) unsigned short highbuf[256*HBS];  // 36864 B
    __shared__ float sf[576];
    __shared__ float sw[1024];
    __shared__ float sb[16];
    __shared__ float redsm[4][8];
    for(int i=t;i<576;i+=256) sf[i] = fsm[(size_t)n*576+i];
    for(int i=t;i<1024;i+=256) sw[i] = w1[i];
    if(t<16) sb[t] = b1[t];
    __syncthreads();
    int rh[3], rw[3];
    #pragma unroll
    for(int k=0;k<3;k++){
        int a = h0 + r0 + 2*(k-1); if(a<0) a=-a; if(a>=Hh) a=2*(Hh-1)-a; rh[k]=a;
        int c = w0 + wl + 2*(k-1); if(c<0) c=-c; if(c>=Ww) c=2*(Ww-1)-c; rw[k]=c;
    }
    const unsigned short* xb = xbf + (size_t)n*HW*64;
    float acc[16];
    #pragma unroll
    for(int o=0;o<16;o++) acc[o]=0.f;
    int wv = t>>6, ln = t&63;
    #pragma unroll 1
    for(int pass=0; pass<2; pass++){
        float low[32];
        #pragma unroll
        for(int i=0;i<32;i++) low[i]=0.f;
        uint4 c4[4];
        #pragma unroll
        for(int t9=0;t9<9;t9++){
            int ki=t9/3, kj=t9%3;
            const uint4* src = (const uint4*)(xb + ((size_t)(rh[ki]*Ww + rw[kj]))*64 + pass*32);
            uint4 v4[4];
            #pragma unroll
            for(int q=0;q<4;q++) v4[q]=src[q];
            if(t9==4){ c4[0]=v4[0]; c4[1]=v4[1]; c4[2]=v4[2]; c4[3]=v4[3]; }
            #pragma unroll
            for(int q=0;q<4;q++){
                unsigned int vv[4]={v4[q].x,v4[q].y,v4[q].z,v4[q].w};
                #pragma unroll
                for(int j=0;j<4;j++){
                    int lc = q*8 + 2*j;
                    int c  = pass*32 + lc;
                    low[lc]   += sf[c*9+t9]    *bf2f(vv[j]&0xffffu);
                    low[lc+1] += sf[(c+1)*9+t9]*bf2f(vv[j]>>16);
                }
            }
        }
        // high + stats (two 16-ch GN groups per pass)
        float sg0=0.f,sq0=0.f,sg1=0.f,sq1=0.f;
        #pragma unroll
        for(int q=0;q<4;q++){
            unsigned int vv[4]={c4[q].x,c4[q].y,c4[q].z,c4[q].w};
            unsigned int hp[4];
            #pragma unroll
            for(int j=0;j<4;j++){
                int lc = q*8 + 2*j;
                float h0v = bf2f(vv[j]&0xffffu) - low[lc];
                float h1v = bf2f(vv[j]>>16)     - low[lc+1];
                if(q<2){ sg0+=h0v+h1v; sq0+=h0v*h0v+h1v*h1v; }
                else   { sg1+=h0v+h1v; sq1+=h0v*h0v+h1v*h1v; }
                hp[j] = (unsigned int)f2bf(h0v) | ((unsigned int)f2bf(h1v)<<16);
            }
            uint4 pk; pk.x=hp[0]; pk.y=hp[1]; pk.z=hp[2]; pk.w=hp[3];
            *(uint4*)&highbuf[t*HBS + (pass*4+q)*8] = pk;
        }
        // y1 partial conv
        #pragma unroll
        for(int o=0;o<16;o++){
            float s=0.f;
            #pragma unroll
            for(int lc=0;lc<32;lc++) s += sw[o*64 + pass*32 + lc]*low[lc];
            acc[o] += s;
        }
        #pragma unroll
        for(int o=32;o>0;o>>=1){
            sg0+=__shfl_down(sg0,o); sq0+=__shfl_down(sq0,o);
            sg1+=__shfl_down(sg1,o); sq1+=__shfl_down(sq1,o);
        }
        if(ln==0){
            redsm[wv][pass*4+0]=sg0; redsm[wv][pass*4+1]=sq0;
            redsm[wv][pass*4+2]=sg1; redsm[wv][pass*4+3]=sq1;
        }
    }
    float a1 = *a1p;
    #pragma unroll
    for(int o=0;o<16;o++){
        float v = acc[o] + sb[o];
        v = v>=0.f ? v : a1*v;
        y1[((size_t)n*16 + o)*HW + (h0+r0)*Ww + w0 + wl] = v;
    }
    __syncthreads();
    // coalesced high writeout: 256 px * 128 B
    uint4* gout = (uint4*)(high + (size_t)n*HW*64);
    #pragma unroll
    for(int it=0;it<8;it++){
        int i = it*256 + t;
        int px = i>>3, sl = i&7;
        uint4 v = *(const uint4*)&highbuf[px*HBS + sl*8];
        gout[((size_t)(h0+(px>>5))*Ww + w0 + (px&31))*8 + sl] = v;
    }
    if(t<8) partial[(size_t)bid*8 + t] = redsm[0][t]+redsm[1][t]+redsm[2][t]+redsm[3][t];
}

// ---------------- kernels 4/5: depthwise3x3(dil) + conv1x1(16->16) + PReLU ----------------
template<int DILT>
__global__ void k_dw_c(const float* __restrict__ yin,
                       const float* __restrict__ dw, const float* __restrict__ db,
                       const float* __restrict__ wc, const float* __restrict__ bc,
                       const float* __restrict__ ap, float* __restrict__ yout){
    int bid = blockIdx.x;
    int n = bid/PIXBLK;
    int pix = (bid%PIXBLK)*256 + threadIdx.x;
    int h = pix/Ww, w = pix%Ww;
    __shared__ float sdw[16*9];
    __shared__ float swc[16*16];
    __shared__ float sdb[16], sbc[16];
    if(threadIdx.x<144) sdw[threadIdx.x] = dw[threadIdx.x];
    if(threadIdx.x>=144 && threadIdx.x<144+16){ sdb[threadIdx.x-144]=db[threadIdx.x-144]; }
    if(threadIdx.x>=160 && threadIdx.x<160+16){ sbc[threadIdx.x-160]=bc[threadIdx.x-160]; }
    for(int i=threadIdx.x;i<256;i+=256) swc[i]=wc[i];
    __syncthreads();
    float t16[16];
    const float* yb = yin + (size_t)n*16*HW;
    for(int c=0;c<16;c++){
        float s = 0.f;
        #pragma unroll
        for(int u=0;u<3;u++){
            int hh = h + DILT*(u-1);
            if(hh<0 || hh>=Hh) continue;
            #pragma unroll
            for(int v=0;v<3;v++){
                int wwi = w + DILT*(v-1);
                if(wwi<0 || wwi>=Ww) continue;
                s += yb[(size_t)c*HW + hh*Ww + wwi]*sdw[c*9+u*3+v];
            }
        }
        t16[c] = s + sdb[c];
    }
    float a = *ap;
    #pragma unroll
    for(int o=0;o<16;o++){
        float s = sbc[o];
        #pragma unroll
        for(int c=0;c<16;c++) s += swc[o*16+c]*t16[c];
        s = s>=0.f ? s : a*s;
        yout[((size_t)n*16 + o)*HW + pix] = s;
    }
}

// ---------------- kernel 6: dw3(dil3)+conv1x1+PReLU+conv1x1(16->64) -> enh_low(bf16,pix-major) ----------------
__global__ void k_dw3_final(const float* __restrict__ yin,
                            const float* __restrict__ dw, const float* __restrict__ db,
                            const float* __restrict__ w4, const float* __restrict__ b4,
                            const float* __restrict__ a4p,
                            const float* __restrict__ w5, const float* __restrict__ b5,
                            unsigned short* __restrict__ enh_low){
    int bid = blockIdx.x;
    int n = bid/PIXBLK;
    int pix = (bid%PIXBLK)*256 + threadIdx.x;
    int h = pix/Ww, w = pix%Ww;
    __shared__ float sdw[16*9];
    __shared__ float sw4[16*16];
    __shared__ float sw5[64*16];
    __shared__ float sdb[16], sb4[16], sb5[64];
    if(threadIdx.x<144) sdw[threadIdx.x]=dw[threadIdx.x];
    if(threadIdx.x<16){ sdb[threadIdx.x]=db[threadIdx.x]; sb4[threadIdx.x]=b4[threadIdx.x]; }
    if(threadIdx.x<64) sb5[threadIdx.x]=b5[threadIdx.x];
    for(int i=threadIdx.x;i<256;i+=256) sw4[i]=w4[i];
    for(int i=threadIdx.x;i<1024;i+=256) sw5[i]=w5[i];
    __syncthreads();
    float t16[16];
    const float* yb = yin + (size_t)n*16*HW;
    for(int c=0;c<16;c++){
        float s=0.f;
        #pragma unroll
        for(int u=0;u<3;u++){
            int hh = h + 3*(u-1);
            if(hh<0||hh>=Hh) continue;
            #pragma unroll
            for(int v=0;v<3;v++){
                int wwi = w + 3*(v-1);
                if(wwi<0||wwi>=Ww) continue;
                s += yb[(size_t)c*HW + hh*Ww + wwi]*sdw[c*9+u*3+v];
            }
        }
        t16[c] = s + sdb[c];
    }
    float a = *a4p;
    float y4[16];
    #pragma unroll
    for(int o=0;o<16;o++){
        float s = sb4[o];
        #pragma unroll
        for(int c=0;c<16;c++) s += sw4[o*16+c]*t16[c];
        y4[o] = s>=0.f ? s : a*s;
    }
    unsigned short* dst = enh_low + ((size_t)n*HW + pix)*64;
    #pragma unroll
    for(int ob=0;ob<64;ob+=4){
        unsigned short tmp[4];
        #pragma unroll
        for(int j=0;j<4;j++){
            int o=ob+j;
            float s = sb5[o];
            #pragma unroll
            for(int c=0;c<16;c++) s += sw5[o*16+c]*y4[c];
            tmp[j]=f2bf(s);
        }
        US4 pk; pk.x=tmp[0]; pk.y=tmp[1]; pk.z=tmp[2]; pk.w=tmp[3];
        *(US4*)&dst[ob] = pk;
    }
}

// ---------------- reduce partials -> st (padded lines) ----------------
__global__ void k_redstats(const float* __restrict__ partial, float* __restrict__ st, int nblk){
    int b = blockIdx.x;                        // 0..15 : n*4+gl
    int n = b>>2, gl = b&3;
    int tid = threadIdx.x;
    float a0=0.f, a1=0.f;
    for(int pt=tid; pt<nblk; pt+=256){
        size_t base = (size_t)(n*nblk+pt)*8 + gl*2;
        a0 += partial[base];
        a1 += partial[base+1];
    }
    #pragma unroll
    for(int o=32;o>0;o>>=1){ a0+=__shfl_down(a0,o); a1+=__shfl_down(a1,o); }
    __shared__ float sm[8];
    int wv=tid>>6, ln=tid&63;
    if(ln==0){ sm[wv*2]=a0; sm[wv*2+1]=a1; }
    __syncthreads();
    if(tid==0){
        st[b*32+0] = sm[0]+sm[2]+sm[4]+sm[6];
        st[b*32+1] = sm[1]+sm[3]+sm[5]+sm[7];
    }
}

// ---------------- kernel 8: conv3x3 64->64 via MFMA, all 64 oc per block ----------------
__global__ void __launch_bounds__(256,3)
k_conv3m(const unsigned short* __restrict__ high, const float* __restrict__ st,
         const float* __restrict__ gng, const float* __restrict__ gnb,
         const unsigned short* __restrict__ g_wt, const float* __restrict__ hb,
         unsigned short* __restrict__ enh_high){
    int bid = blockIdx.x;
    int n = bid/144, tile = bid%144;
    int tr0 = (tile/12)*16, tc0 = (tile%12)*16;
    __shared__ __align__(16) unsigned short z_lds[324*64];     // 41472 B
    __shared__ float ssc[64], sbi[64], sbias[64];
    int tid = threadIdx.x;
    if(tid<64){
        int c=tid, g=n*4+(c>>4);
        float cnt=16.f*(float)HW;
        float m=st[g*32]/cnt, var=st[g*32+1]/cnt-m*m;
        float sc=gng[c]*rsqrtf(var+1e-5f);
        ssc[c]=sc; sbi[c]=gnb[c]-m*sc;
        sbias[c]=hb[c];
    }
    __syncthreads();
    const uint4* hpm = (const uint4*)(high + (size_t)n*HW*64);
    for(int e=tid;e<2592;e+=256){
        int hpx = e>>3, q = e&7;
        int hr = hpx/18, hc = hpx - hr*18;
        int gr = tr0+hr-1, gc = tc0+hc-1;
        uint4 w; w.x=0; w.y=0; w.z=0; w.w=0;
        if(gr>=0 && gr<Hh && gc>=0 && gc<Ww){
            uint4 v = hpm[(size_t)(gr*Ww+gc)*8 + q];
            unsigned int vv[4]={v.x,v.y,v.z,v.w};
            #pragma unroll
            for(int j=0;j<4;j++){
                int c = q*8 + 2*j;
                float f0 = bf2f(vv[j]&0xffffu)*ssc[c]   + sbi[c];
                float f1 = bf2f(vv[j]>>16)   *ssc[c+1] + sbi[c+1];
                f0 = f0>=0.f ? f0 : 0.01f*f0;
                f1 = f1>=0.f ? f1 : 0.01f*f1;
                vv[j] = (unsigned int)f2bf(f0) | ((unsigned int)f2bf(f1)<<16);
            }
            w.x=vv[0]; w.y=vv[1]; w.z=vv[2]; w.w=vv[3];
        }
        *(uint4*)&z_lds[hpx*64 + ((q*8) ^ ((hpx&7)<<3))] = w;
    }
    __syncthreads();
    int wv = tid>>6, ln = tid&63;
    int col = ln&15, kq = ln>>4;
    f32x4 acc[4][4];                            // [og][rf]
    #pragma unroll
    for(int og=0;og<4;og++)
        #pragma unroll
        for(int rf=0;rf<4;rf++) acc[og][rf]=(f32x4){0.f,0.f,0.f,0.f};
    #pragma unroll
    for(int t=0;t<9;t++){
        int dr = t/3 - 1, dc = t%3 - 1;
        #pragma unroll
        for(int kb=0;kb<2;kb++){
            int k0 = kb*32 + kq*8;
            s16x8 afr[4];
            #pragma unroll
            for(int og=0;og<4;og++)
                afr[og] = *(const s16x8*)&g_wt[(size_t)(((og*9+t)*16+col)*64) + k0];
            #pragma unroll
            for(int rf=0;rf<4;rf++){
                int r = wv*4 + rf;
                int hpx = (r+1+dr)*18 + (col+1+dc);
                const s16x8 bfr = *(const s16x8*)&z_lds[hpx*64 + (k0 ^ ((hpx&7)<<3))];
                #pragma unroll
                for(int og=0;og<4;og++)
                    acc[og][rf] = __builtin_amdgcn_mfma_f32_16x16x32_bf16(afr[og], bfr, acc[og][rf], 0, 0, 0);
            }
        }
    }
    const unsigned short* hres = high + (size_t)n*HW*64;
    #pragma unroll
    for(int rf=0;rf<4;rf++){
        int r = wv*4 + rf;
        int gpx = (tr0+r)*Ww + (tc0+col);
        #pragma unroll
        for(int og=0;og<4;og++){
            US4 rv = *(const US4*)&hres[(size_t)gpx*64 + og*16 + kq*4];
            float rvf[4] = {bf2f(rv.x), bf2f(rv.y), bf2f(rv.z), bf2f(rv.w)};
            unsigned short tmp[4];
            #pragma unroll
            for(int reg=0;reg<4;reg++){
                int oc = og*16 + kq*4 + reg;
                tmp[reg] = f2bf(acc[og][rf][reg] + sbias[oc] + rvf[reg]);
            }
            US4 pk; pk.x=tmp[0]; pk.y=tmp[1]; pk.z=tmp[2]; pk.w=tmp[3];
            *(US4*)&enh_high[((size_t)n*HW + gpx)*64 + og*16 + kq*4] = pk;
        }
    }
}

// ---------------- kernel 9: fusion conv1x1 128->128 via MFMA + per-block stat partials ----------------
__global__ void __launch_bounds__(256,2)
k_fu1m(const unsigned short* __restrict__ el, const unsigned short* __restrict__ eh,
       const unsigned short* __restrict__ wA, const float* __restrict__ b,
       unsigned short* __restrict__ o1, float* __restrict__ partial){
    int bid = blockIdx.x;
    int n = bid/288, pt = bid%288;
    int px0 = pt*128;
    __shared__ __align__(16) unsigned short sA[128*128];   // 32 KB
    __shared__ __align__(16) unsigned short sB[128*128];   // 32 KB
    __shared__ float sb[128];
    __shared__ float redsm[16];
    int tid = threadIdx.x;
    {
        const uint4* s=(const uint4*)wA; uint4* d=(uint4*)sA;
        for(int i=tid;i<2048;i+=256) d[i]=s[i];
    }
    if(tid<128) sb[tid]=b[tid];
    {
        const uint4* se=(const uint4*)(el + ((size_t)n*HW+px0)*64);
        const uint4* sh=(const uint4*)(eh + ((size_t)n*HW+px0)*64);
        for(int i=tid;i<2048;i+=256){
            int px=i>>4, q=i&15;
            uint4 v = (q<8)? se[px*8+q] : sh[px*8+(q-8)];
            int c0 = q*8;
            *(uint4*)&sB[px*128 + (c0 ^ ((px&15)<<3))] = v;
        }
    }
    __syncthreads();
    int wv=tid>>6, ln=tid&63;
    int wm=wv>>1, wn=wv&1;
    int col=ln&15, kq=ln>>4;
    f32x4 acc[4][4];
    #pragma unroll
    for(int m=0;m<4;m++)
        #pragma unroll
        for(int nf=0;nf<4;nf++) acc[m][nf]=(f32x4){0.f,0.f,0.f,0.f};
    #pragma unroll
    for(int kb=0;kb<4;kb++){
        int k0 = kb*32 + kq*8;
        s16x8 a[4], bf[4];
        #pragma unroll
        for(int m=0;m<4;m++)
            a[m] = *(const s16x8*)&sA[(wm*64+m*16+col)*128 + (k0 ^ (col<<3))];
        #pragma unroll
        for(int nf=0;nf<4;nf++)
            bf[nf] = *(const s16x8*)&sB[(wn*64+nf*16+col)*128 + (k0 ^ (col<<3))];
        #pragma unroll
        for(int m=0;m<4;m++)
            #pragma unroll
            for(int nf=0;nf<4;nf++)
                acc[m][nf] = __builtin_amdgcn_mfma_f32_16x16x32_bf16(a[m], bf[nf], acc[m][nf], 0,0,0);
    }
    float sg0=0.f,sq0=0.f,sg1=0.f,sq1=0.f;
    #pragma unroll
    for(int m=0;m<4;m++){
        int oc0 = wm*64 + m*16 + kq*4;
        #pragma unroll
        for(int nf=0;nf<4;nf++){
            int px = wn*64 + nf*16 + col;
            unsigned short tmp[4];
            #pragma unroll
            for(int reg=0;reg<4;reg++){
                float v = acc[m][nf][reg] + sb[oc0+reg];
                if(m<2){ sg0+=v; sq0+=v*v; } else { sg1+=v; sq1+=v*v; }
                tmp[reg]=f2bf(v);
            }
            US4 pk; pk.x=tmp[0]; pk.y=tmp[1]; pk.z=tmp[2]; pk.w=tmp[3];
            *(US4*)&o1[((size_t)n*HW + px0 + px)*128 + oc0] = pk;
        }
    }
    #pragma unroll
    for(int o=32;o>0;o>>=1){
        sg0+=__shfl_down(sg0,o); sq0+=__shfl_down(sq0,o);
        sg1+=__shfl_down(sg1,o); sq1+=__shfl_down(sq1,o);
    }
    if(ln==0){ redsm[wv*4+0]=sg0; redsm[wv*4+1]=sq0; redsm[wv*4+2]=sg1; redsm[wv*4+3]=sq1; }
    __syncthreads();
    if(tid<8){
        int gl = tid>>1, comp = tid&1;
        int wbase = (gl>>1)*2;
        int off = (gl&1)*2 + comp;
        partial[(size_t)bid*8 + tid] = redsm[wbase*4+off] + redsm[(wbase+1)*4+off];
    }
}

// ---------------- kernel 10: GN + GELU + conv1x1 128->64 via MFMA -> out(f32) ----------------
__global__ void __launch_bounds__(256,2)
k_fu2m(const unsigned short* __restrict__ o1, const float* __restrict__ st,
       const float* __restrict__ gg, const float* __restrict__ gb,
       const unsigned short* __restrict__ wA, const float* __restrict__ b2,
       float* __restrict__ out){
    int bid = blockIdx.x;
    int n = bid/288, pt = bid%288;
    int px0 = pt*128;
    __shared__ __align__(16) unsigned short sA[64*128];    // 16 KB
    __shared__ __align__(16) unsigned short sB[128*128];   // 32 KB
    __shared__ float ssc[128], sbi[128], sb2[64];
    int tid = threadIdx.x;
    {
        const uint4* s=(const uint4*)wA; uint4* d=(uint4*)sA;
        for(int i=tid;i<1024;i+=256) d[i]=s[i];
    }
    if(tid<128){
        int c=tid, g=n*4+(c>>5);
        float cnt = 32.f*(float)HW;
        float m = st[g*32]/cnt;
        float var = st[g*32+1]/cnt - m*m;
        float sc = gg[c]*rsqrtf(var+1e-5f);
        ssc[c]=sc; sbi[c]=gb[c]-m*sc;
    }
    if(tid<64) sb2[tid]=b2[tid];
    __syncthreads();
    {
        const uint4* so=(const uint4*)(o1 + ((size_t)n*HW+px0)*128);
        for(int i=tid;i<2048;i+=256){
            int px=i>>4, q=i&15;
            int c0 = q*8;
            uint4 v = so[px*16+q];
            unsigned int vals[4] = {v.x,v.y,v.z,v.w};
            #pragma unroll
            for(int j=0;j<4;j++){
                int c = c0 + 2*j;
                float f0 = bf2f(vals[j]&0xffffu)*ssc[c]   + sbi[c];
                float f1 = bf2f(vals[j]>>16)   *ssc[c+1] + sbi[c+1];
                f0 = 0.5f*f0*(1.f+erff(f0*0.70710678118654752f));
                f1 = 0.5f*f1*(1.f+erff(f1*0.70710678118654752f));
                vals[j] = (unsigned int)f2bf(f0) | ((unsigned int)f2bf(f1)<<16);
            }
            uint4 w; w.x=vals[0]; w.y=vals[1]; w.z=vals[2]; w.w=vals[3];
            *(uint4*)&sB[px*128 + (c0 ^ ((px&15)<<3))] = w;
        }
    }
    __syncthreads();
    int wv=tid>>6, ln=tid&63;
    int col=ln&15, kq=ln>>4;
    f32x4 acc[4][2];
    #pragma unroll
    for(int m=0;m<4;m++){ acc[m][0]=(f32x4){0,0,0,0}; acc[m][1]=(f32x4){0,0,0,0}; }
    #pragma unroll
    for(int kb=0;kb<4;kb++){
        int k0 = kb*32 + kq*8;
        s16x8 a[4], bf[2];
        #pragma unroll
        for(int m=0;m<4;m++)
            a[m] = *(const s16x8*)&sA[(m*16+col)*128 + (k0 ^ (col<<3))];
        #pragma unroll
        for(int nf=0;nf<2;nf++)
            bf[nf] = *(const s16x8*)&sB[(wv*32+nf*16+col)*128 + (k0 ^ (col<<3))];
        #pragma unroll
        for(int m=0;m<4;m++)
            #pragma unroll
            for(int nf=0;nf<2;nf++)
                acc[m][nf] = __builtin_amdgcn_mfma_f32_16x16x32_bf16(a[m], bf[nf], acc[m][nf], 0,0,0);
    }
    #pragma unroll
    for(int m=0;m<4;m++){
        int oc0 = m*16 + kq*4;
        #pragma unroll
        for(int nf=0;nf<2;nf++){
            int px = px0 + wv*32 + nf*16 + col;
            #pragma unroll
            for(int reg=0;reg<4;reg++){
                int oc = oc0+reg;
                out[((size_t)n*64+oc)*HW + px] = acc[m][nf][reg] + sb2[oc];
            }
        }
    }
}

extern "C" void kernel_launch(void* const* d_in, const int* in_sizes, int n_in,
                              void* d_out, int out_size, void* d_ws, size_t ws_size,
                              hipStream_t stream) {
    const float* x        = (const float*)d_in[0];
    const float* w_filter = (const float*)d_in[1];
    const float* gnf_g    = (const float*)d_in[2];
    const float* gnf_b    = (const float*)d_in[3];
    const float* lb_w1    = (const float*)d_in[4];
    const float* lb_b1    = (const float*)d_in[5];
    const float* lb_a1    = (const float*)d_in[6];
    const float* lb_dw1   = (const float*)d_in[7];
    const float* lb_db1   = (const float*)d_in[8];
    const float* lb_w2    = (const float*)d_in[9];
    const float* lb_b2    = (const float*)d_in[10];
    const float* lb_a2    = (const float*)d_in[11];
    const float* lb_dw2   = (const float*)d_in[12];
    const float* lb_db2   = (const float*)d_in[13];
    const float* lb_w3    = (const float*)d_in[14];
    const float* lb_b3    = (const float*)d_in[15];
    const float* lb_a3    = (const float*)d_in[16];
    const float* lb_dw3   = (const float*)d_in[17];
    const float* lb_db3   = (const float*)d_in[18];
    const float* lb_w4    = (const float*)d_in[19];
    const float* lb_b4    = (const float*)d_in[20];
    const float* lb_a4    = (const float*)d_in[21];
    const float* lb_w5    = (const float*)d_in[22];
    const float* lb_b5    = (const float*)d_in[23];
    const float* hb_gn_g  = (const float*)d_in[24];
    const float* hb_gn_b  = (const float*)d_in[25];
    const float* hb_w     = (const float*)d_in[26];
    const float* hb_b     = (const float*)d_in[27];
    const float* fu_w1    = (const float*)d_in[28];
    const float* fu_b1    = (const float*)d_in[29];
    const float* fu_gn_g  = (const float*)d_in[30];
    const float* fu_gn_b  = (const float*)d_in[31];
    const float* fu_w2    = (const float*)d_in[32];
    const float* fu_b2    = (const float*)d_in[33];
    float* out = (float*)d_out;

    // ws layout (bytes)
    const size_t O1B = (size_t)Nn*HW*128*2;     // 37,748,736  o1 bf16 [n][px][128]
    const size_t EB  = (size_t)Nn*HW*64*2;      // 18,874,368  bf16 [n][px][64]
    const size_t YB  = (size_t)Nn*16*HW*4;      // 9,437,184   f32 planar
    char* Wb = (char*)d_ws;
    unsigned short* o1       = (unsigned short*)Wb;               // [0, O1B)
    unsigned short* high     = (unsigned short*)Wb;               // aliases o1 (dead before fu1m writes)
    unsigned short* enh_low  = (unsigned short*)(Wb + O1B);
    unsigned short* enh_high = (unsigned short*)(Wb + O1B + EB);
    float* y1                = (float*)(Wb + O1B + 2*EB);
    float* y2                = (float*)(Wb + O1B + 2*EB + YB);
    unsigned short* g_wt     = (unsigned short*)(Wb + O1B + 2*EB + 2*YB); // 36864 ush
    unsigned short* g_wfu1   = g_wt + 36864;                              // 16384 ush
    unsigned short* g_wfu2   = g_wfu1 + 16384;                            // 8192 ush
    float* fp      = (float*)(g_wfu2 + 8192);
    float* fsm     = fp + 256;
    float* st_hb   = fsm + 2304;       // 16 groups * 32 floats (padded lines)
    float* st_o1   = st_hb + 512;      // 16 groups * 32 floats
    float* part_hb = st_o1 + 512;      // 576 * 8 floats
    float* part_o1 = part_hb + 4608;   // 1152 * 8 floats
    unsigned short* xbf = (unsigned short*)(part_o1 + 9216);              // bf16 [n][px][64]

    k_xprep<<<Nn*144, 256, 0, stream>>>(x, xbf);
    k_prep<<<496, 256, 0, stream>>>(hb_w, fu_w1, fu_w2, x, g_wt, g_wfu1, g_wfu2, fp);
    k_filter<<<Nn, 576, 0, stream>>>(fp, w_filter, gnf_g, gnf_b, fsm);
    k_lowhigh<<<Nn*144, 256, 0, stream>>>(xbf, fsm, lb_w1, lb_b1, lb_a1, high, y1, part_hb);
    k_redstats<<<16, 256, 0, stream>>>(part_hb, st_hb, 144);
    k_conv3m<<<Nn*144, 256, 0, stream>>>(high, st_hb, hb_gn_g, hb_gn_b, g_wt, hb_b, enh_high);
    k_dw_c<5><<<Nn*PIXBLK, 256, 0, stream>>>(y1, lb_dw1, lb_db1, lb_w2, lb_b2, lb_a2, y2);
    k_dw_c<1><<<Nn*PIXBLK, 256, 0, stream>>>(y2, lb_dw2, lb_db2, lb_w3, lb_b3, lb_a3, y1);
    k_dw3_final<<<Nn*PIXBLK, 256, 0, stream>>>(y1, lb_dw3, lb_db3, lb_w4, lb_b4, lb_a4,
                                               lb_w5, lb_b5, enh_low);
    k_fu1m<<<Nn*288, 256, 0, stream>>>(enh_low, enh_high, g_wfu1, fu_b1, o1, part_o1);
    k_redstats<<<16, 256, 0, stream>>>(part_o1, st_o1, 288);
    k_fu2m<<<Nn*288, 256, 0, stream>>>(o1, st_o1, fu_gn_g, fu_gn_b, g_wfu2, fu_b2, out);
}

// Round 10
// 540.934 us; speedup vs baseline: 1.3195x; 1.3195x over previous
//
#include <hip/hip_runtime.h>
#include <hip/hip_bf16.h>
#include <math.h>

#define Nn 4
#define Cc 64
#define Hh 192
#define Ww 192
#define HW (Hh*Ww)          // 36864
#define PIXBLK 144          // HW/256

typedef __attribute__((ext_vector_type(4))) float f32x4;
typedef __attribute__((ext_vector_type(8))) short s16x8;

struct __align__(8) US4 { unsigned short x,y,z,w; };

static __device__ __forceinline__ unsigned short f2bf(float v){
    __hip_bfloat16 b = __float2bfloat16(v);
    return *(unsigned short*)&b;
}
static __device__ __forceinline__ float bf2f(unsigned int u){
    return __uint_as_float(u<<16);
}

// ---------------- kernel 0: x -> bf16 pixel-major [n][px][64] ----------------
__global__ void k_xprep(const float* __restrict__ x, unsigned short* __restrict__ xbf){
    int bid = blockIdx.x;              // Nn*144
    int n = bid/144, chunk = bid%144;
    int px = chunk*256 + threadIdx.x;
    const float* xb = x + (size_t)n*Cc*HW + px;
    unsigned int pk[32];
    #pragma unroll
    for(int c2=0;c2<32;c2++){
        float f0 = xb[(size_t)(2*c2)*HW];
        float f1 = xb[(size_t)(2*c2+1)*HW];
        pk[c2] = (unsigned int)f2bf(f0) | ((unsigned int)f2bf(f1)<<16);
    }
    uint4* dst = (uint4*)(xbf + ((size_t)n*HW + px)*64);
    #pragma unroll
    for(int q=0;q<8;q++){
        uint4 v; v.x=pk[q*4]; v.y=pk[q*4+1]; v.z=pk[q*4+2]; v.w=pk[q*4+3];
        dst[q] = v;
    }
}

// ---------------- kernel 1: weight prep (240 blocks) + global average pool (256 blocks) ----------------
__global__ void k_prep(const float* __restrict__ hw, const float* __restrict__ fw1,
                       const float* __restrict__ fw2, const float* __restrict__ x,
                       unsigned short* __restrict__ g_wt,
                       unsigned short* __restrict__ g_wfu1,
                       unsigned short* __restrict__ g_wfu2,
                       float* __restrict__ fp){
    int b = blockIdx.x;
    __shared__ float sm[4];
    if(b < 240){
        int idx = b*256 + threadIdx.x;    // 0..61439
        if(idx<36864){
            int og = idx/9216, r = idx%9216;
            int t = r/1024, r2 = r%1024;
            int o = r2>>6, c = r2&63;
            g_wt[idx] = f2bf(hw[(size_t)(((og*16+o)*64)+c)*9 + t]);
        } else if(idx<53248){
            int i = idx-36864;
            int o = i>>7, c = i&127;
            g_wfu1[o*128 + (c ^ ((o&15)<<3))] = f2bf(fw1[i]);
        } else {
            int i = idx-53248;
            int o = i>>7, c = i&127;
            g_wfu2[o*128 + (c ^ ((o&15)<<3))] = f2bf(fw2[i]);
        }
    } else {
        int nc = b-240;                    // 0..255
        const float4* p = (const float4*)(x + (size_t)nc*HW);
        float s = 0.f;
        for(int i=threadIdx.x;i<HW/4;i+=256){ float4 v=p[i]; s += v.x+v.y+v.z+v.w; }
        for(int o=32;o>0;o>>=1) s += __shfl_down(s,o);
        int wid = threadIdx.x>>6, ln = threadIdx.x&63;
        if(ln==0) sm[wid]=s;
        __syncthreads();
        if(threadIdx.x==0) fp[nc] = (sm[0]+sm[1]+sm[2]+sm[3]) / (float)HW;
    }
}

// ---------------- kernel 2: dynamic filter (matvec + GN + softmax) ----------------
__global__ void k_filter(const float* __restrict__ fp, const float* __restrict__ wf,
                         const float* __restrict__ gg, const float* __restrict__ gb,
                         float* __restrict__ fsm){
    int n = blockIdx.x;
    __shared__ float sfp[64];
    __shared__ float sfw[576];
    __shared__ float gstat[8];
    int t = threadIdx.x;                       // 0..575
    if(t<64) sfp[t] = fp[n*64+t];
    __syncthreads();
    const float* wr = wf + (size_t)t*64;
    float acc = 0.f;
    #pragma unroll 8
    for(int k=0;k<64;k++) acc += sfp[k]*wr[k];
    sfw[t] = acc;
    __syncthreads();
    if(t<4){
        float s=0.f,s2=0.f;
        for(int i=0;i<144;i++){ float v=sfw[t*144+i]; s+=v; s2+=v*v; }
        float m = s/144.f;
        gstat[t*2]   = m;
        gstat[t*2+1] = s2/144.f - m*m;
    }
    __syncthreads();
    int g = t/144;
    float m = gstat[g*2], var = gstat[g*2+1];
    float z = (acc-m)*rsqrtf(var+1e-5f)*gg[t] + gb[t];
    sfw[t] = z;
    __syncthreads();
    if(t<64){
        float mx = -1e30f;
        for(int j=0;j<9;j++) mx = fmaxf(mx, sfw[t*9+j]);
        float e[9]; float se=0.f;
        for(int j=0;j<9;j++){ e[j]=expf(sfw[t*9+j]-mx); se+=e[j]; }
        float inv = 1.f/se;
        for(int j=0;j<9;j++) fsm[((size_t)n*64+t)*9+j] = e[j]*inv;
    }
}

// ---------------- kernel 3: low/high + conv1x1(64->16)+PReLU + high GN partials ----------------
// 32x8 tiles, 1 px/thread, 576 blocks; xbf pixel-major bf16; OCTET-wise (8 ch at a time),
// all named scalars -> no scratch spill (R9 lesson: 414MB spill traffic from wide arrays).
#define HBS 72
__global__ void __launch_bounds__(256,2)
k_lowhigh(const unsigned short* __restrict__ xbf, const float* __restrict__ fsm,
          const float* __restrict__ w1, const float* __restrict__ b1,
          const float* __restrict__ a1p,
          unsigned short* __restrict__ high, float* __restrict__ y1,
          float* __restrict__ partial){
    int bid = blockIdx.x;
    int n = bid/144, tile = bid%144;
    int h0 = (tile/6)*8, w0 = (tile%6)*32;
    int t = threadIdx.x;
    int r0 = t>>5, wl = t&31;
    __shared__ __align__(16) unsigned short highbuf[256*HBS];  // 36864 B
    __shared__ float sf[576];
    __shared__ float sw[1024];
    __shared__ float sb[16];
    __shared__ float redsm[4][8];
    for(int i=t;i<576;i+=256) sf[i] = fsm[(size_t)n*576+i];
    for(int i=t;i<1024;i+=256) sw[i] = w1[i];
    if(t<16) sb[t] = b1[t];
    __syncthreads();
    // reflect tap offsets (named scalars; byte offsets into xbf rows)
    int a0=h0+r0-2, a1=h0+r0, a2=h0+r0+2;
    if(a0<0)a0=-a0; if(a2>=Hh)a2=2*(Hh-1)-a2;
    int c0w=w0+wl-2, c1w=w0+wl, c2w=w0+wl+2;
    if(c0w<0)c0w=-c0w; if(c2w>=Ww)c2w=2*(Ww-1)-c2w;
    const unsigned short* xb = xbf + (size_t)n*HW*64;
    // 9 tap base pointers (uint4 index): (row*Ww+col)*8
    size_t tp0=((size_t)a0*Ww+c0w)*8, tp1=((size_t)a0*Ww+c1w)*8, tp2=((size_t)a0*Ww+c2w)*8;
    size_t tp3=((size_t)a1*Ww+c0w)*8, tp4=((size_t)a1*Ww+c1w)*8, tp5=((size_t)a1*Ww+c2w)*8;
    size_t tp6=((size_t)a2*Ww+c0w)*8, tp7=((size_t)a2*Ww+c1w)*8, tp8=((size_t)a2*Ww+c2w)*8;
    const uint4* xq = (const uint4*)xb;
    float acc[16];
    #pragma unroll
    for(int o=0;o<16;o++) acc[o]=0.f;
    int wv = t>>6, ln = t&63;
    #pragma unroll 1
    for(int grp=0; grp<4; grp++){
        float sg=0.f, sq=0.f;
        #pragma unroll
        for(int sub=0; sub<2; sub++){
            const int oct = grp*2+sub;
            float l0=0,l1=0,l2=0,l3=0,l4=0,l5=0,l6=0,l7=0;
            unsigned int cx=0,cy=0,cz=0,cw=0;
            const float* sfo = &sf[oct*8*9];
            #pragma unroll
            for(int t9=0;t9<9;t9++){
                size_t tb = (t9==0)?tp0:(t9==1)?tp1:(t9==2)?tp2:(t9==3)?tp3:
                            (t9==4)?tp4:(t9==5)?tp5:(t9==6)?tp6:(t9==7)?tp7:tp8;
                const uint4 v = xq[tb + oct];
                if(t9==4){ cx=v.x; cy=v.y; cz=v.z; cw=v.w; }
                l0 += sfo[0*9+t9]*bf2f(v.x&0xffffu);
                l1 += sfo[1*9+t9]*bf2f(v.x>>16);
                l2 += sfo[2*9+t9]*bf2f(v.y&0xffffu);
                l3 += sfo[3*9+t9]*bf2f(v.y>>16);
                l4 += sfo[4*9+t9]*bf2f(v.z&0xffffu);
                l5 += sfo[5*9+t9]*bf2f(v.z>>16);
                l6 += sfo[6*9+t9]*bf2f(v.w&0xffffu);
                l7 += sfo[7*9+t9]*bf2f(v.w>>16);
            }
            float h0v=bf2f(cx&0xffffu)-l0, h1v=bf2f(cx>>16)-l1;
            float h2v=bf2f(cy&0xffffu)-l2, h3v=bf2f(cy>>16)-l3;
            float h4v=bf2f(cz&0xffffu)-l4, h5v=bf2f(cz>>16)-l5;
            float h6v=bf2f(cw&0xffffu)-l6, h7v=bf2f(cw>>16)-l7;
            sg += h0v+h1v+h2v+h3v+h4v+h5v+h6v+h7v;
            sq += h0v*h0v+h1v*h1v+h2v*h2v+h3v*h3v+h4v*h4v+h5v*h5v+h6v*h6v+h7v*h7v;
            uint4 pk;
            pk.x = (unsigned int)f2bf(h0v) | ((unsigned int)f2bf(h1v)<<16);
            pk.y = (unsigned int)f2bf(h2v) | ((unsigned int)f2bf(h3v)<<16);
            pk.z = (unsigned int)f2bf(h4v) | ((unsigned int)f2bf(h5v)<<16);
            pk.w = (unsigned int)f2bf(h6v) | ((unsigned int)f2bf(h7v)<<16);
            *(uint4*)&highbuf[t*HBS + oct*8] = pk;
            const float* swo = &sw[oct*8];
            #pragma unroll
            for(int o=0;o<16;o++){
                acc[o] += swo[o*64+0]*l0 + swo[o*64+1]*l1 + swo[o*64+2]*l2 + swo[o*64+3]*l3
                        + swo[o*64+4]*l4 + swo[o*64+5]*l5 + swo[o*64+6]*l6 + swo[o*64+7]*l7;
            }
        }
        #pragma unroll
        for(int o=32;o>0;o>>=1){ sg+=__shfl_down(sg,o); sq+=__shfl_down(sq,o); }
        if(ln==0){ redsm[wv][grp*2]=sg; redsm[wv][grp*2+1]=sq; }
    }
    float a1p_ = *a1p;
    #pragma unroll
    for(int o=0;o<16;o++){
        float v = acc[o] + sb[o];
        v = v>=0.f ? v : a1p_*v;
        y1[((size_t)n*16 + o)*HW + (h0+r0)*Ww + w0 + wl] = v;
    }
    __syncthreads();
    // coalesced high writeout: 256 px * 128 B
    uint4* gout = (uint4*)(high + (size_t)n*HW*64);
    #pragma unroll
    for(int it=0;it<8;it++){
        int i = it*256 + t;
        int px = i>>3, sl = i&7;
        uint4 v = *(const uint4*)&highbuf[px*HBS + sl*8];
        gout[((size_t)(h0+(px>>5))*Ww + w0 + (px&31))*8 + sl] = v;
    }
    if(t<8) partial[(size_t)bid*8 + t] = redsm[0][t]+redsm[1][t]+redsm[2][t]+redsm[3][t];
}

// ---------------- kernels 4/5: depthwise3x3(dil) + conv1x1(16->16) + PReLU ----------------
template<int DILT>
__global__ void k_dw_c(const float* __restrict__ yin,
                       const float* __restrict__ dw, const float* __restrict__ db,
                       const float* __restrict__ wc, const float* __restrict__ bc,
                       const float* __restrict__ ap, float* __restrict__ yout){
    int bid = blockIdx.x;
    int n = bid/PIXBLK;
    int pix = (bid%PIXBLK)*256 + threadIdx.x;
    int h = pix/Ww, w = pix%Ww;
    __shared__ float sdw[16*9];
    __shared__ float swc[16*16];
    __shared__ float sdb[16], sbc[16];
    if(threadIdx.x<144) sdw[threadIdx.x] = dw[threadIdx.x];
    if(threadIdx.x>=144 && threadIdx.x<144+16){ sdb[threadIdx.x-144]=db[threadIdx.x-144]; }
    if(threadIdx.x>=160 && threadIdx.x<160+16){ sbc[threadIdx.x-160]=bc[threadIdx.x-160]; }
    for(int i=threadIdx.x;i<256;i+=256) swc[i]=wc[i];
    __syncthreads();
    float t16[16];
    const float* yb = yin + (size_t)n*16*HW;
    for(int c=0;c<16;c++){
        float s = 0.f;
        #pragma unroll
        for(int u=0;u<3;u++){
            int hh = h + DILT*(u-1);
            if(hh<0 || hh>=Hh) continue;
            #pragma unroll
            for(int v=0;v<3;v++){
                int wwi = w + DILT*(v-1);
                if(wwi<0 || wwi>=Ww) continue;
                s += yb[(size_t)c*HW + hh*Ww + wwi]*sdw[c*9+u*3+v];
            }
        }
        t16[c] = s + sdb[c];
    }
    float a = *ap;
    #pragma unroll
    for(int o=0;o<16;o++){
        float s = sbc[o];
        #pragma unroll
        for(int c=0;c<16;c++) s += swc[o*16+c]*t16[c];
        s = s>=0.f ? s : a*s;
        yout[((size_t)n*16 + o)*HW + pix] = s;
    }
}

// ---------------- kernel 6: dw3(dil3)+conv1x1+PReLU+conv1x1(16->64) -> enh_low(bf16,pix-major) ----------------
__global__ void k_dw3_final(const float* __restrict__ yin,
                            const float* __restrict__ dw, const float* __restrict__ db,
                            const float* __restrict__ w4, const float* __restrict__ b4,
                            const float* __restrict__ a4p,
                            const float* __restrict__ w5, const float* __restrict__ b5,
                            unsigned short* __restrict__ enh_low){
    int bid = blockIdx.x;
    int n = bid/PIXBLK;
    int pix = (bid%PIXBLK)*256 + threadIdx.x;
    int h = pix/Ww, w = pix%Ww;
    __shared__ float sdw[16*9];
    __shared__ float sw4[16*16];
    __shared__ float sw5[64*16];
    __shared__ float sdb[16], sb4[16], sb5[64];
    if(threadIdx.x<144) sdw[threadIdx.x]=dw[threadIdx.x];
    if(threadIdx.x<16){ sdb[threadIdx.x]=db[threadIdx.x]; sb4[threadIdx.x]=b4[threadIdx.x]; }
    if(threadIdx.x<64) sb5[threadIdx.x]=b5[threadIdx.x];
    for(int i=threadIdx.x;i<256;i+=256) sw4[i]=w4[i];
    for(int i=threadIdx.x;i<1024;i+=256) sw5[i]=w5[i];
    __syncthreads();
    float t16[16];
    const float* yb = yin + (size_t)n*16*HW;
    for(int c=0;c<16;c++){
        float s=0.f;
        #pragma unroll
        for(int u=0;u<3;u++){
            int hh = h + 3*(u-1);
            if(hh<0||hh>=Hh) continue;
            #pragma unroll
            for(int v=0;v<3;v++){
                int wwi = w + 3*(v-1);
                if(wwi<0||wwi>=Ww) continue;
                s += yb[(size_t)c*HW + hh*Ww + wwi]*sdw[c*9+u*3+v];
            }
        }
        t16[c] = s + sdb[c];
    }
    float a = *a4p;
    float y4[16];
    #pragma unroll
    for(int o=0;o<16;o++){
        float s = sb4[o];
        #pragma unroll
        for(int c=0;c<16;c++) s += sw4[o*16+c]*t16[c];
        y4[o] = s>=0.f ? s : a*s;
    }
    unsigned short* dst = enh_low + ((size_t)n*HW + pix)*64;
    #pragma unroll
    for(int ob=0;ob<64;ob+=4){
        unsigned short tmp[4];
        #pragma unroll
        for(int j=0;j<4;j++){
            int o=ob+j;
            float s = sb5[o];
            #pragma unroll
            for(int c=0;c<16;c++) s += sw5[o*16+c]*y4[c];
            tmp[j]=f2bf(s);
        }
        US4 pk; pk.x=tmp[0]; pk.y=tmp[1]; pk.z=tmp[2]; pk.w=tmp[3];
        *(US4*)&dst[ob] = pk;
    }
}

// ---------------- reduce partials -> st (padded lines) ----------------
__global__ void k_redstats(const float* __restrict__ partial, float* __restrict__ st, int nblk){
    int b = blockIdx.x;                        // 0..15 : n*4+gl
    int n = b>>2, gl = b&3;
    int tid = threadIdx.x;
    float a0=0.f, a1=0.f;
    for(int pt=tid; pt<nblk; pt+=256){
        size_t base = (size_t)(n*nblk+pt)*8 + gl*2;
        a0 += partial[base];
        a1 += partial[base+1];
    }
    #pragma unroll
    for(int o=32;o>0;o>>=1){ a0+=__shfl_down(a0,o); a1+=__shfl_down(a1,o); }
    __shared__ float sm[8];
    int wv=tid>>6, ln=tid&63;
    if(ln==0){ sm[wv*2]=a0; sm[wv*2+1]=a1; }
    __syncthreads();
    if(tid==0){
        st[b*32+0] = sm[0]+sm[2]+sm[4]+sm[6];
        st[b*32+1] = sm[1]+sm[3]+sm[5]+sm[7];
    }
}

// ---------------- kernel 8: conv3x3 64->64 via MFMA, all 64 oc per block ----------------
__global__ void __launch_bounds__(256,3)
k_conv3m(const unsigned short* __restrict__ high, const float* __restrict__ st,
         const float* __restrict__ gng, const float* __restrict__ gnb,
         const unsigned short* __restrict__ g_wt, const float* __restrict__ hb,
         unsigned short* __restrict__ enh_high){
    int bid = blockIdx.x;
    int n = bid/144, tile = bid%144;
    int tr0 = (tile/12)*16, tc0 = (tile%12)*16;
    __shared__ __align__(16) unsigned short z_lds[324*64];     // 41472 B
    __shared__ float ssc[64], sbi[64], sbias[64];
    int tid = threadIdx.x;
    if(tid<64){
        int c=tid, g=n*4+(c>>4);
        float cnt=16.f*(float)HW;
        float m=st[g*32]/cnt, var=st[g*32+1]/cnt-m*m;
        float sc=gng[c]*rsqrtf(var+1e-5f);
        ssc[c]=sc; sbi[c]=gnb[c]-m*sc;
        sbias[c]=hb[c];
    }
    __syncthreads();
    const uint4* hpm = (const uint4*)(high + (size_t)n*HW*64);
    for(int e=tid;e<2592;e+=256){
        int hpx = e>>3, q = e&7;
        int hr = hpx/18, hc = hpx - hr*18;
        int gr = tr0+hr-1, gc = tc0+hc-1;
        uint4 w; w.x=0; w.y=0; w.z=0; w.w=0;
        if(gr>=0 && gr<Hh && gc>=0 && gc<Ww){
            uint4 v = hpm[(size_t)(gr*Ww+gc)*8 + q];
            unsigned int vv[4]={v.x,v.y,v.z,v.w};
            #pragma unroll
            for(int j=0;j<4;j++){
                int c = q*8 + 2*j;
                float f0 = bf2f(vv[j]&0xffffu)*ssc[c]   + sbi[c];
                float f1 = bf2f(vv[j]>>16)   *ssc[c+1] + sbi[c+1];
                f0 = f0>=0.f ? f0 : 0.01f*f0;
                f1 = f1>=0.f ? f1 : 0.01f*f1;
                vv[j] = (unsigned int)f2bf(f0) | ((unsigned int)f2bf(f1)<<16);
            }
            w.x=vv[0]; w.y=vv[1]; w.z=vv[2]; w.w=vv[3];
        }
        *(uint4*)&z_lds[hpx*64 + ((q*8) ^ ((hpx&7)<<3))] = w;
    }
    __syncthreads();
    int wv = tid>>6, ln = tid&63;
    int col = ln&15, kq = ln>>4;
    f32x4 acc[4][4];                            // [og][rf]
    #pragma unroll
    for(int og=0;og<4;og++)
        #pragma unroll
        for(int rf=0;rf<4;rf++) acc[og][rf]=(f32x4){0.f,0.f,0.f,0.f};
    #pragma unroll
    for(int t=0;t<9;t++){
        int dr = t/3 - 1, dc = t%3 - 1;
        #pragma unroll
        for(int kb=0;kb<2;kb++){
            int k0 = kb*32 + kq*8;
            s16x8 afr[4];
            #pragma unroll
            for(int og=0;og<4;og++)
                afr[og] = *(const s16x8*)&g_wt[(size_t)(((og*9+t)*16+col)*64) + k0];
            #pragma unroll
            for(int rf=0;rf<4;rf++){
                int r = wv*4 + rf;
                int hpx = (r+1+dr)*18 + (col+1+dc);
                const s16x8 bfr = *(const s16x8*)&z_lds[hpx*64 + (k0 ^ ((hpx&7)<<3))];
                #pragma unroll
                for(int og=0;og<4;og++)
                    acc[og][rf] = __builtin_amdgcn_mfma_f32_16x16x32_bf16(afr[og], bfr, acc[og][rf], 0, 0, 0);
            }
        }
    }
    const unsigned short* hres = high + (size_t)n*HW*64;
    #pragma unroll
    for(int rf=0;rf<4;rf++){
        int r = wv*4 + rf;
        int gpx = (tr0+r)*Ww + (tc0+col);
        #pragma unroll
        for(int og=0;og<4;og++){
            US4 rv = *(const US4*)&hres[(size_t)gpx*64 + og*16 + kq*4];
            float rvf[4] = {bf2f(rv.x), bf2f(rv.y), bf2f(rv.z), bf2f(rv.w)};
            unsigned short tmp[4];
            #pragma unroll
            for(int reg=0;reg<4;reg++){
                int oc = og*16 + kq*4 + reg;
                tmp[reg] = f2bf(acc[og][rf][reg] + sbias[oc] + rvf[reg]);
            }
            US4 pk; pk.x=tmp[0]; pk.y=tmp[1]; pk.z=tmp[2]; pk.w=tmp[3];
            *(US4*)&enh_high[((size_t)n*HW + gpx)*64 + og*16 + kq*4] = pk;
        }
    }
}

// ---------------- kernel 9: fusion conv1x1 128->128 via MFMA + per-block stat partials ----------------
__global__ void __launch_bounds__(256,2)
k_fu1m(const unsigned short* __restrict__ el, const unsigned short* __restrict__ eh,
       const unsigned short* __restrict__ wA, const float* __restrict__ b,
       unsigned short* __restrict__ o1, float* __restrict__ partial){
    int bid = blockIdx.x;
    int n = bid/288, pt = bid%288;
    int px0 = pt*128;
    __shared__ __align__(16) unsigned short sA[128*128];   // 32 KB
    __shared__ __align__(16) unsigned short sB[128*128];   // 32 KB
    __shared__ float sb[128];
    __shared__ float redsm[16];
    int tid = threadIdx.x;
    {
        const uint4* s=(const uint4*)wA; uint4* d=(uint4*)sA;
        for(int i=tid;i<2048;i+=256) d[i]=s[i];
    }
    if(tid<128) sb[tid]=b[tid];
    {
        const uint4* se=(const uint4*)(el + ((size_t)n*HW+px0)*64);
        const uint4* sh=(const uint4*)(eh + ((size_t)n*HW+px0)*64);
        for(int i=tid;i<2048;i+=256){
            int px=i>>4, q=i&15;
            uint4 v = (q<8)? se[px*8+q] : sh[px*8+(q-8)];
            int c0 = q*8;
            *(uint4*)&sB[px*128 + (c0 ^ ((px&15)<<3))] = v;
        }
    }
    __syncthreads();
    int wv=tid>>6, ln=tid&63;
    int wm=wv>>1, wn=wv&1;
    int col=ln&15, kq=ln>>4;
    f32x4 acc[4][4];
    #pragma unroll
    for(int m=0;m<4;m++)
        #pragma unroll
        for(int nf=0;nf<4;nf++) acc[m][nf]=(f32x4){0.f,0.f,0.f,0.f};
    #pragma unroll
    for(int kb=0;kb<4;kb++){
        int k0 = kb*32 + kq*8;
        s16x8 a[4], bf[4];
        #pragma unroll
        for(int m=0;m<4;m++)
            a[m] = *(const s16x8*)&sA[(wm*64+m*16+col)*128 + (k0 ^ (col<<3))];
        #pragma unroll
        for(int nf=0;nf<4;nf++)
            bf[nf] = *(const s16x8*)&sB[(wn*64+nf*16+col)*128 + (k0 ^ (col<<3))];
        #pragma unroll
        for(int m=0;m<4;m++)
            #pragma unroll
            for(int nf=0;nf<4;nf++)
                acc[m][nf] = __builtin_amdgcn_mfma_f32_16x16x32_bf16(a[m], bf[nf], acc[m][nf], 0,0,0);
    }
    float sg0=0.f,sq0=0.f,sg1=0.f,sq1=0.f;
    #pragma unroll
    for(int m=0;m<4;m++){
        int oc0 = wm*64 + m*16 + kq*4;
        #pragma unroll
        for(int nf=0;nf<4;nf++){
            int px = wn*64 + nf*16 + col;
            unsigned short tmp[4];
            #pragma unroll
            for(int reg=0;reg<4;reg++){
                float v = acc[m][nf][reg] + sb[oc0+reg];
                if(m<2){ sg0+=v; sq0+=v*v; } else { sg1+=v; sq1+=v*v; }
                tmp[reg]=f2bf(v);
            }
            US4 pk; pk.x=tmp[0]; pk.y=tmp[1]; pk.z=tmp[2]; pk.w=tmp[3];
            *(US4*)&o1[((size_t)n*HW + px0 + px)*128 + oc0] = pk;
        }
    }
    #pragma unroll
    for(int o=32;o>0;o>>=1){
        sg0+=__shfl_down(sg0,o); sq0+=__shfl_down(sq0,o);
        sg1+=__shfl_down(sg1,o); sq1+=__shfl_down(sq1,o);
    }
    if(ln==0){ redsm[wv*4+0]=sg0; redsm[wv*4+1]=sq0; redsm[wv*4+2]=sg1; redsm[wv*4+3]=sq1; }
    __syncthreads();
    if(tid<8){
        int gl = tid>>1, comp = tid&1;
        int wbase = (gl>>1)*2;
        int off = (gl&1)*2 + comp;
        partial[(size_t)bid*8 + tid] = redsm[wbase*4+off] + redsm[(wbase+1)*4+off];
    }
}

// ---------------- kernel 10: GN + GELU + conv1x1 128->64 via MFMA -> out(f32) ----------------
__global__ void __launch_bounds__(256,2)
k_fu2m(const unsigned short* __restrict__ o1, const float* __restrict__ st,
       const float* __restrict__ gg, const float* __restrict__ gb,
       const unsigned short* __restrict__ wA, const float* __restrict__ b2,
       float* __restrict__ out){
    int bid = blockIdx.x;
    int n = bid/288, pt = bid%288;
    int px0 = pt*128;
    __shared__ __align__(16) unsigned short sA[64*128];    // 16 KB
    __shared__ __align__(16) unsigned short sB[128*128];   // 32 KB
    __shared__ float ssc[128], sbi[128], sb2[64];
    int tid = threadIdx.x;
    {
        const uint4* s=(const uint4*)wA; uint4* d=(uint4*)sA;
        for(int i=tid;i<1024;i+=256) d[i]=s[i];
    }
    if(tid<128){
        int c=tid, g=n*4+(c>>5);
        float cnt = 32.f*(float)HW;
        float m = st[g*32]/cnt;
        float var = st[g*32+1]/cnt - m*m;
        float sc = gg[c]*rsqrtf(var+1e-5f);
        ssc[c]=sc; sbi[c]=gb[c]-m*sc;
    }
    if(tid<64) sb2[tid]=b2[tid];
    __syncthreads();
    {
        const uint4* so=(const uint4*)(o1 + ((size_t)n*HW+px0)*128);
        for(int i=tid;i<2048;i+=256){
            int px=i>>4, q=i&15;
            int c0 = q*8;
            uint4 v = so[px*16+q];
            unsigned int vals[4] = {v.x,v.y,v.z,v.w};
            #pragma unroll
            for(int j=0;j<4;j++){
                int c = c0 + 2*j;
                float f0 = bf2f(vals[j]&0xffffu)*ssc[c]   + sbi[c];
                float f1 = bf2f(vals[j]>>16)   *ssc[c+1] + sbi[c+1];
                f0 = 0.5f*f0*(1.f+erff(f0*0.70710678118654752f));
                f1 = 0.5f*f1*(1.f+erff(f1*0.70710678118654752f));
                vals[j] = (unsigned int)f2bf(f0) | ((unsigned int)f2bf(f1)<<16);
            }
            uint4 w; w.x=vals[0]; w.y=vals[1]; w.z=vals[2]; w.w=vals[3];
            *(uint4*)&sB[px*128 + (c0 ^ ((px&15)<<3))] = w;
        }
    }
    __syncthreads();
    int wv=tid>>6, ln=tid&63;
    int col=ln&15, kq=ln>>4;
    f32x4 acc[4][2];
    #pragma unroll
    for(int m=0;m<4;m++){ acc[m][0]=(f32x4){0,0,0,0}; acc[m][1]=(f32x4){0,0,0,0}; }
    #pragma unroll
    for(int kb=0;kb<4;kb++){
        int k0 = kb*32 + kq*8;
        s16x8 a[4], bf[2];
        #pragma unroll
        for(int m=0;m<4;m++)
            a[m] = *(const s16x8*)&sA[(m*16+col)*128 + (k0 ^ (col<<3))];
        #pragma unroll
        for(int nf=0;nf<2;nf++)
            bf[nf] = *(const s16x8*)&sB[(wv*32+nf*16+col)*128 + (k0 ^ (col<<3))];
        #pragma unroll
        for(int m=0;m<4;m++)
            #pragma unroll
            for(int nf=0;nf<2;nf++)
                acc[m][nf] = __builtin_amdgcn_mfma_f32_16x16x32_bf16(a[m], bf[nf], acc[m][nf], 0,0,0);
    }
    #pragma unroll
    for(int m=0;m<4;m++){
        int oc0 = m*16 + kq*4;
        #pragma unroll
        for(int nf=0;nf<2;nf++){
            int px = px0 + wv*32 + nf*16 + col;
            #pragma unroll
            for(int reg=0;reg<4;reg++){
                int oc = oc0+reg;
                out[((size_t)n*64+oc)*HW + px] = acc[m][nf][reg] + sb2[oc];
            }
        }
    }
}

extern "C" void kernel_launch(void* const* d_in, const int* in_sizes, int n_in,
                              void* d_out, int out_size, void* d_ws, size_t ws_size,
                              hipStream_t stream) {
    const float* x        = (const float*)d_in[0];
    const float* w_filter = (const float*)d_in[1];
    const float* gnf_g    = (const float*)d_in[2];
    const float* gnf_b    = (const float*)d_in[3];
    const float* lb_w1    = (const float*)d_in[4];
    const float* lb_b1    = (const float*)d_in[5];
    const float* lb_a1    = (const float*)d_in[6];
    const float* lb_dw1   = (const float*)d_in[7];
    const float* lb_db1   = (const float*)d_in[8];
    const float* lb_w2    = (const float*)d_in[9];
    const float* lb_b2    = (const float*)d_in[10];
    const float* lb_a2    = (const float*)d_in[11];
    const float* lb_dw2   = (const float*)d_in[12];
    const float* lb_db2   = (const float*)d_in[13];
    const float* lb_w3    = (const float*)d_in[14];
    const float* lb_b3    = (const float*)d_in[15];
    const float* lb_a3    = (const float*)d_in[16];
    const float* lb_dw3   = (const float*)d_in[17];
    const float* lb_db3   = (const float*)d_in[18];
    const float* lb_w4    = (const float*)d_in[19];
    const float* lb_b4    = (const float*)d_in[20];
    const float* lb_a4    = (const float*)d_in[21];
    const float* lb_w5    = (const float*)d_in[22];
    const float* lb_b5    = (const float*)d_in[23];
    const float* hb_gn_g  = (const float*)d_in[24];
    const float* hb_gn_b  = (const float*)d_in[25];
    const float* hb_w     = (const float*)d_in[26];
    const float* hb_b     = (const float*)d_in[27];
    const float* fu_w1    = (const float*)d_in[28];
    const float* fu_b1    = (const float*)d_in[29];
    const float* fu_gn_g  = (const float*)d_in[30];
    const float* fu_gn_b  = (const float*)d_in[31];
    const float* fu_w2    = (const float*)d_in[32];
    const float* fu_b2    = (const float*)d_in[33];
    float* out = (float*)d_out;

    // ws layout (bytes)
    const size_t O1B = (size_t)Nn*HW*128*2;     // 37,748,736  o1 bf16 [n][px][128]
    const size_t EB  = (size_t)Nn*HW*64*2;      // 18,874,368  bf16 [n][px][64]
    const size_t YB  = (size_t)Nn*16*HW*4;      // 9,437,184   f32 planar
    char* Wb = (char*)d_ws;
    unsigned short* o1       = (unsigned short*)Wb;               // [0, O1B)
    unsigned short* high     = (unsigned short*)Wb;               // aliases o1 (dead before fu1m writes)
    unsigned short* enh_low  = (unsigned short*)(Wb + O1B);
    unsigned short* enh_high = (unsigned short*)(Wb + O1B + EB);
    float* y1                = (float*)(Wb + O1B + 2*EB);
    float* y2                = (float*)(Wb + O1B + 2*EB + YB);
    unsigned short* g_wt     = (unsigned short*)(Wb + O1B + 2*EB + 2*YB); // 36864 ush
    unsigned short* g_wfu1   = g_wt + 36864;                              // 16384 ush
    unsigned short* g_wfu2   = g_wfu1 + 16384;                            // 8192 ush
    float* fp      = (float*)(g_wfu2 + 8192);
    float* fsm     = fp + 256;
    float* st_hb   = fsm + 2304;       // 16 groups * 32 floats (padded lines)
    float* st_o1   = st_hb + 512;      // 16 groups * 32 floats
    float* part_hb = st_o1 + 512;      // 576 * 8 floats
    float* part_o1 = part_hb + 4608;   // 1152 * 8 floats
    unsigned short* xbf = (unsigned short*)(part_o1 + 9216);              // bf16 [n][px][64]

    k_xprep<<<Nn*144, 256, 0, stream>>>(x, xbf);
    k_prep<<<496, 256, 0, stream>>>(hb_w, fu_w1, fu_w2, x, g_wt, g_wfu1, g_wfu2, fp);
    k_filter<<<Nn, 576, 0, stream>>>(fp, w_filter, gnf_g, gnf_b, fsm);
    k_lowhigh<<<Nn*144, 256, 0, stream>>>(xbf, fsm, lb_w1, lb_b1, lb_a1, high, y1, part_hb);
    k_redstats<<<16, 256, 0, stream>>>(part_hb, st_hb, 144);
    k_conv3m<<<Nn*144, 256, 0, stream>>>(high, st_hb, hb_gn_g, hb_gn_b, g_wt, hb_b, enh_high);
    k_dw_c<5><<<Nn*PIXBLK, 256, 0, stream>>>(y1, lb_dw1, lb_db1, lb_w2, lb_b2, lb_a2, y2);
    k_dw_c<1><<<Nn*PIXBLK, 256, 0, stream>>>(y2, lb_dw2, lb_db2, lb_w3, lb_b3, lb_a3, y1);
    k_dw3_final<<<Nn*PIXBLK, 256, 0, stream>>>(y1, lb_dw3, lb_db3, lb_w4, lb_b4, lb_a4,
                                               lb_w5, lb_b5, enh_low);
    k_fu1m<<<Nn*288, 256, 0, stream>>>(enh_low, enh_high, g_wfu1, fu_b1, o1, part_o1);
    k_redstats<<<16, 256, 0, stream>>>(part_o1, st_o1, 288);
    k_fu2m<<<Nn*288, 256, 0, stream>>>(o1, st_o1, fu_gn_g, fu_gn_b, g_wfu2, fu_b2, out);
}

// Round 11
// 486.624 us; speedup vs baseline: 1.4668x; 1.1116x over previous
//
#include <hip/hip_runtime.h>
#include <hip/hip_bf16.h>
#include <math.h>

#define Nn 4
#define Cc 64
#define Hh 192
#define Ww 192
#define HW (Hh*Ww)          // 36864
#define PIXBLK 144          // HW/256

typedef __attribute__((ext_vector_type(4))) float f32x4;
typedef __attribute__((ext_vector_type(8))) short s16x8;

struct __align__(8) US4 { unsigned short x,y,z,w; };

static __device__ __forceinline__ unsigned short f2bf(float v){
    __hip_bfloat16 b = __float2bfloat16(v);
    return *(unsigned short*)&b;
}
static __device__ __forceinline__ float bf2f(unsigned int u){
    return __uint_as_float(u<<16);
}

// ---------------- kernel 0: x -> bf16 pixel-major [n][px][64] ----------------
__global__ void k_xprep(const float* __restrict__ x, unsigned short* __restrict__ xbf){
    int bid = blockIdx.x;              // Nn*144
    int n = bid/144, chunk = bid%144;
    int px = chunk*256 + threadIdx.x;
    const float* xb = x + (size_t)n*Cc*HW + px;
    unsigned int pk[32];
    #pragma unroll
    for(int c2=0;c2<32;c2++){
        float f0 = xb[(size_t)(2*c2)*HW];
        float f1 = xb[(size_t)(2*c2+1)*HW];
        pk[c2] = (unsigned int)f2bf(f0) | ((unsigned int)f2bf(f1)<<16);
    }
    uint4* dst = (uint4*)(xbf + ((size_t)n*HW + px)*64);
    #pragma unroll
    for(int q=0;q<8;q++){
        uint4 v; v.x=pk[q*4]; v.y=pk[q*4+1]; v.z=pk[q*4+2]; v.w=pk[q*4+3];
        dst[q] = v;
    }
}

// ---------------- kernel 1: weight prep (240 blocks) + global average pool (256 blocks) ----------------
__global__ void k_prep(const float* __restrict__ hw, const float* __restrict__ fw1,
                       const float* __restrict__ fw2, const float* __restrict__ x,
                       unsigned short* __restrict__ g_wt,
                       unsigned short* __restrict__ g_wfu1,
                       unsigned short* __restrict__ g_wfu2,
                       float* __restrict__ fp){
    int b = blockIdx.x;
    __shared__ float sm[4];
    if(b < 240){
        int idx = b*256 + threadIdx.x;    // 0..61439
        if(idx<36864){
            int og = idx/9216, r = idx%9216;
            int t = r/1024, r2 = r%1024;
            int o = r2>>6, c = r2&63;
            g_wt[idx] = f2bf(hw[(size_t)(((og*16+o)*64)+c)*9 + t]);
        } else if(idx<53248){
            int i = idx-36864;
            int o = i>>7, c = i&127;
            g_wfu1[o*128 + (c ^ ((o&15)<<3))] = f2bf(fw1[i]);
        } else {
            int i = idx-53248;
            int o = i>>7, c = i&127;
            g_wfu2[o*128 + (c ^ ((o&15)<<3))] = f2bf(fw2[i]);
        }
    } else {
        int nc = b-240;                    // 0..255
        const float4* p = (const float4*)(x + (size_t)nc*HW);
        float s = 0.f;
        for(int i=threadIdx.x;i<HW/4;i+=256){ float4 v=p[i]; s += v.x+v.y+v.z+v.w; }
        for(int o=32;o>0;o>>=1) s += __shfl_down(s,o);
        int wid = threadIdx.x>>6, ln = threadIdx.x&63;
        if(ln==0) sm[wid]=s;
        __syncthreads();
        if(threadIdx.x==0) fp[nc] = (sm[0]+sm[1]+sm[2]+sm[3]) / (float)HW;
    }
}

// ---------------- kernel 2: dynamic filter (matvec + GN + softmax) ----------------
__global__ void k_filter(const float* __restrict__ fp, const float* __restrict__ wf,
                         const float* __restrict__ gg, const float* __restrict__ gb,
                         float* __restrict__ fsm){
    int n = blockIdx.x;
    __shared__ float sfp[64];
    __shared__ float sfw[576];
    __shared__ float gstat[8];
    int t = threadIdx.x;                       // 0..575
    if(t<64) sfp[t] = fp[n*64+t];
    __syncthreads();
    const float* wr = wf + (size_t)t*64;
    float acc = 0.f;
    #pragma unroll 8
    for(int k=0;k<64;k++) acc += sfp[k]*wr[k];
    sfw[t] = acc;
    __syncthreads();
    if(t<4){
        float s=0.f,s2=0.f;
        for(int i=0;i<144;i++){ float v=sfw[t*144+i]; s+=v; s2+=v*v; }
        float m = s/144.f;
        gstat[t*2]   = m;
        gstat[t*2+1] = s2/144.f - m*m;
    }
    __syncthreads();
    int g = t/144;
    float m = gstat[g*2], var = gstat[g*2+1];
    float z = (acc-m)*rsqrtf(var+1e-5f)*gg[t] + gb[t];
    sfw[t] = z;
    __syncthreads();
    if(t<64){
        float mx = -1e30f;
        for(int j=0;j<9;j++) mx = fmaxf(mx, sfw[t*9+j]);
        float e[9]; float se=0.f;
        for(int j=0;j<9;j++){ e[j]=expf(sfw[t*9+j]-mx); se+=e[j]; }
        float inv = 1.f/se;
        for(int j=0;j<9;j++) fsm[((size_t)n*64+t)*9+j] = e[j]*inv;
    }
}

// ---------------- kernel 3: low/high + conv1x1(64->16)+PReLU + high GN partials ----------------
// 32x8 tiles, 1 px/thread, 576 blocks; xbf pixel-major bf16; octet-wise named scalars.
// XCD-swizzled (576%8==0): each XCD gets 72 contiguous tiles -> L2-local halo reuse.
// launch_bounds(256,1): no 128-VGPR cap -> no scratch spill (R10 lesson).
#define HBS 72
__global__ void __launch_bounds__(256,1)
k_lowhigh(const unsigned short* __restrict__ xbf, const float* __restrict__ fsm,
          const float* __restrict__ w1, const float* __restrict__ b1,
          const float* __restrict__ a1p,
          unsigned short* __restrict__ high, float* __restrict__ y1,
          float* __restrict__ partial){
    int bid0 = blockIdx.x;
    int bid = (bid0&7)*72 + (bid0>>3);         // XCD-contiguous work id (bijective, 576=8*72)
    int n = bid/144, tile = bid%144;
    int h0 = (tile/6)*8, w0 = (tile%6)*32;
    int t = threadIdx.x;
    int r0 = t>>5, wl = t&31;
    __shared__ __align__(16) unsigned short highbuf[256*HBS];  // 36864 B
    __shared__ float sf[576];
    __shared__ float sw[1024];
    __shared__ float sb[16];
    __shared__ float redsm[4][8];
    for(int i=t;i<576;i+=256) sf[i] = fsm[(size_t)n*576+i];
    for(int i=t;i<1024;i+=256) sw[i] = w1[i];
    if(t<16) sb[t] = b1[t];
    __syncthreads();
    // reflect tap offsets
    int a0=h0+r0-2, a1=h0+r0, a2=h0+r0+2;
    if(a0<0)a0=-a0; if(a2>=Hh)a2=2*(Hh-1)-a2;
    int c0w=w0+wl-2, c1w=w0+wl, c2w=w0+wl+2;
    if(c0w<0)c0w=-c0w; if(c2w>=Ww)c2w=2*(Ww-1)-c2w;
    const unsigned short* xb = xbf + (size_t)n*HW*64;
    // 9 tap base offsets (uint4 index, 32-bit: max 36863*8 < 2^19)
    unsigned tp0=(unsigned)(a0*Ww+c0w)*8u, tp1=(unsigned)(a0*Ww+c1w)*8u, tp2=(unsigned)(a0*Ww+c2w)*8u;
    unsigned tp3=(unsigned)(a1*Ww+c0w)*8u, tp4=(unsigned)(a1*Ww+c1w)*8u, tp5=(unsigned)(a1*Ww+c2w)*8u;
    unsigned tp6=(unsigned)(a2*Ww+c0w)*8u, tp7=(unsigned)(a2*Ww+c1w)*8u, tp8=(unsigned)(a2*Ww+c2w)*8u;
    const uint4* xq = (const uint4*)xb;
    float acc[16];
    #pragma unroll
    for(int o=0;o<16;o++) acc[o]=0.f;
    int wv = t>>6, ln = t&63;
    #pragma unroll 1
    for(int grp=0; grp<4; grp++){
        float sg=0.f, sq=0.f;
        #pragma unroll
        for(int sub=0; sub<2; sub++){
            const int oct = grp*2+sub;
            float l0=0,l1=0,l2=0,l3=0,l4=0,l5=0,l6=0,l7=0;
            unsigned int cx=0,cy=0,cz=0,cw=0;
            const float* sfo = &sf[oct*8*9];
            #pragma unroll
            for(int t9=0;t9<9;t9++){
                unsigned tb = (t9==0)?tp0:(t9==1)?tp1:(t9==2)?tp2:(t9==3)?tp3:
                              (t9==4)?tp4:(t9==5)?tp5:(t9==6)?tp6:(t9==7)?tp7:tp8;
                const uint4 v = xq[tb + (unsigned)oct];
                if(t9==4){ cx=v.x; cy=v.y; cz=v.z; cw=v.w; }
                l0 += sfo[0*9+t9]*bf2f(v.x&0xffffu);
                l1 += sfo[1*9+t9]*bf2f(v.x>>16);
                l2 += sfo[2*9+t9]*bf2f(v.y&0xffffu);
                l3 += sfo[3*9+t9]*bf2f(v.y>>16);
                l4 += sfo[4*9+t9]*bf2f(v.z&0xffffu);
                l5 += sfo[5*9+t9]*bf2f(v.z>>16);
                l6 += sfo[6*9+t9]*bf2f(v.w&0xffffu);
                l7 += sfo[7*9+t9]*bf2f(v.w>>16);
            }
            float h0v=bf2f(cx&0xffffu)-l0, h1v=bf2f(cx>>16)-l1;
            float h2v=bf2f(cy&0xffffu)-l2, h3v=bf2f(cy>>16)-l3;
            float h4v=bf2f(cz&0xffffu)-l4, h5v=bf2f(cz>>16)-l5;
            float h6v=bf2f(cw&0xffffu)-l6, h7v=bf2f(cw>>16)-l7;
            sg += h0v+h1v+h2v+h3v+h4v+h5v+h6v+h7v;
            sq += h0v*h0v+h1v*h1v+h2v*h2v+h3v*h3v+h4v*h4v+h5v*h5v+h6v*h6v+h7v*h7v;
            uint4 pk;
            pk.x = (unsigned int)f2bf(h0v) | ((unsigned int)f2bf(h1v)<<16);
            pk.y = (unsigned int)f2bf(h2v) | ((unsigned int)f2bf(h3v)<<16);
            pk.z = (unsigned int)f2bf(h4v) | ((unsigned int)f2bf(h5v)<<16);
            pk.w = (unsigned int)f2bf(h6v) | ((unsigned int)f2bf(h7v)<<16);
            *(uint4*)&highbuf[t*HBS + oct*8] = pk;
            const float* swo = &sw[oct*8];
            #pragma unroll
            for(int o=0;o<16;o++){
                acc[o] += swo[o*64+0]*l0 + swo[o*64+1]*l1 + swo[o*64+2]*l2 + swo[o*64+3]*l3
                        + swo[o*64+4]*l4 + swo[o*64+5]*l5 + swo[o*64+6]*l6 + swo[o*64+7]*l7;
            }
        }
        #pragma unroll
        for(int o=32;o>0;o>>=1){ sg+=__shfl_down(sg,o); sq+=__shfl_down(sq,o); }
        if(ln==0){ redsm[wv][grp*2]=sg; redsm[wv][grp*2+1]=sq; }
    }
    float a1p_ = *a1p;
    #pragma unroll
    for(int o=0;o<16;o++){
        float v = acc[o] + sb[o];
        v = v>=0.f ? v : a1p_*v;
        y1[((size_t)n*16 + o)*HW + (h0+r0)*Ww + w0 + wl] = v;
    }
    __syncthreads();
    // coalesced high writeout: 256 px * 128 B
    uint4* gout = (uint4*)(high + (size_t)n*HW*64);
    #pragma unroll
    for(int it=0;it<8;it++){
        int i = it*256 + t;
        int px = i>>3, sl = i&7;
        uint4 v = *(const uint4*)&highbuf[px*HBS + sl*8];
        gout[((size_t)(h0+(px>>5))*Ww + w0 + (px&31))*8 + sl] = v;
    }
    if(t<8) partial[(size_t)bid*8 + t] = redsm[0][t]+redsm[1][t]+redsm[2][t]+redsm[3][t];
}

// ---------------- kernels 4/5: depthwise3x3(dil) + conv1x1(16->16) + PReLU ----------------
template<int DILT>
__global__ void k_dw_c(const float* __restrict__ yin,
                       const float* __restrict__ dw, const float* __restrict__ db,
                       const float* __restrict__ wc, const float* __restrict__ bc,
                       const float* __restrict__ ap, float* __restrict__ yout){
    int bid = blockIdx.x;
    int n = bid/PIXBLK;
    int pix = (bid%PIXBLK)*256 + threadIdx.x;
    int h = pix/Ww, w = pix%Ww;
    __shared__ float sdw[16*9];
    __shared__ float swc[16*16];
    __shared__ float sdb[16], sbc[16];
    if(threadIdx.x<144) sdw[threadIdx.x] = dw[threadIdx.x];
    if(threadIdx.x>=144 && threadIdx.x<144+16){ sdb[threadIdx.x-144]=db[threadIdx.x-144]; }
    if(threadIdx.x>=160 && threadIdx.x<160+16){ sbc[threadIdx.x-160]=bc[threadIdx.x-160]; }
    for(int i=threadIdx.x;i<256;i+=256) swc[i]=wc[i];
    __syncthreads();
    float t16[16];
    const float* yb = yin + (size_t)n*16*HW;
    for(int c=0;c<16;c++){
        float s = 0.f;
        #pragma unroll
        for(int u=0;u<3;u++){
            int hh = h + DILT*(u-1);
            if(hh<0 || hh>=Hh) continue;
            #pragma unroll
            for(int v=0;v<3;v++){
                int wwi = w + DILT*(v-1);
                if(wwi<0 || wwi>=Ww) continue;
                s += yb[(size_t)c*HW + hh*Ww + wwi]*sdw[c*9+u*3+v];
            }
        }
        t16[c] = s + sdb[c];
    }
    float a = *ap;
    #pragma unroll
    for(int o=0;o<16;o++){
        float s = sbc[o];
        #pragma unroll
        for(int c=0;c<16;c++) s += swc[o*16+c]*t16[c];
        s = s>=0.f ? s : a*s;
        yout[((size_t)n*16 + o)*HW + pix] = s;
    }
}

// ---------------- kernel 6: dw3(dil3)+conv1x1+PReLU+conv1x1(16->64) -> enh_low(bf16,pix-major) ----------------
__global__ void k_dw3_final(const float* __restrict__ yin,
                            const float* __restrict__ dw, const float* __restrict__ db,
                            const float* __restrict__ w4, const float* __restrict__ b4,
                            const float* __restrict__ a4p,
                            const float* __restrict__ w5, const float* __restrict__ b5,
                            unsigned short* __restrict__ enh_low){
    int bid = blockIdx.x;
    int n = bid/PIXBLK;
    int pix = (bid%PIXBLK)*256 + threadIdx.x;
    int h = pix/Ww, w = pix%Ww;
    __shared__ float sdw[16*9];
    __shared__ float sw4[16*16];
    __shared__ float sw5[64*16];
    __shared__ float sdb[16], sb4[16], sb5[64];
    if(threadIdx.x<144) sdw[threadIdx.x]=dw[threadIdx.x];
    if(threadIdx.x<16){ sdb[threadIdx.x]=db[threadIdx.x]; sb4[threadIdx.x]=b4[threadIdx.x]; }
    if(threadIdx.x<64) sb5[threadIdx.x]=b5[threadIdx.x];
    for(int i=threadIdx.x;i<256;i+=256) sw4[i]=w4[i];
    for(int i=threadIdx.x;i<1024;i+=256) sw5[i]=w5[i];
    __syncthreads();
    float t16[16];
    const float* yb = yin + (size_t)n*16*HW;
    for(int c=0;c<16;c++){
        float s=0.f;
        #pragma unroll
        for(int u=0;u<3;u++){
            int hh = h + 3*(u-1);
            if(hh<0||hh>=Hh) continue;
            #pragma unroll
            for(int v=0;v<3;v++){
                int wwi = w + 3*(v-1);
                if(wwi<0||wwi>=Ww) continue;
                s += yb[(size_t)c*HW + hh*Ww + wwi]*sdw[c*9+u*3+v];
            }
        }
        t16[c] = s + sdb[c];
    }
    float a = *a4p;
    float y4[16];
    #pragma unroll
    for(int o=0;o<16;o++){
        float s = sb4[o];
        #pragma unroll
        for(int c=0;c<16;c++) s += sw4[o*16+c]*t16[c];
        y4[o] = s>=0.f ? s : a*s;
    }
    unsigned short* dst = enh_low + ((size_t)n*HW + pix)*64;
    #pragma unroll
    for(int ob=0;ob<64;ob+=4){
        unsigned short tmp[4];
        #pragma unroll
        for(int j=0;j<4;j++){
            int o=ob+j;
            float s = sb5[o];
            #pragma unroll
            for(int c=0;c<16;c++) s += sw5[o*16+c]*y4[c];
            tmp[j]=f2bf(s);
        }
        US4 pk; pk.x=tmp[0]; pk.y=tmp[1]; pk.z=tmp[2]; pk.w=tmp[3];
        *(US4*)&dst[ob] = pk;
    }
}

// ---------------- reduce partials -> st (padded lines) ----------------
__global__ void k_redstats(const float* __restrict__ partial, float* __restrict__ st, int nblk){
    int b = blockIdx.x;                        // 0..15 : n*4+gl
    int n = b>>2, gl = b&3;
    int tid = threadIdx.x;
    float a0=0.f, a1=0.f;
    for(int pt=tid; pt<nblk; pt+=256){
        size_t base = (size_t)(n*nblk+pt)*8 + gl*2;
        a0 += partial[base];
        a1 += partial[base+1];
    }
    #pragma unroll
    for(int o=32;o>0;o>>=1){ a0+=__shfl_down(a0,o); a1+=__shfl_down(a1,o); }
    __shared__ float sm[8];
    int wv=tid>>6, ln=tid&63;
    if(ln==0){ sm[wv*2]=a0; sm[wv*2+1]=a1; }
    __syncthreads();
    if(tid==0){
        st[b*32+0] = sm[0]+sm[2]+sm[4]+sm[6];
        st[b*32+1] = sm[1]+sm[3]+sm[5]+sm[7];
    }
}

// ---------------- kernel 8: conv3x3 64->64 via MFMA, all 64 oc per block (XCD-swizzled) ----------------
__global__ void __launch_bounds__(256,3)
k_conv3m(const unsigned short* __restrict__ high, const float* __restrict__ st,
         const float* __restrict__ gng, const float* __restrict__ gnb,
         const unsigned short* __restrict__ g_wt, const float* __restrict__ hb,
         unsigned short* __restrict__ enh_high){
    int bid0 = blockIdx.x;
    int bid = (bid0&7)*72 + (bid0>>3);         // XCD-contiguous work id
    int n = bid/144, tile = bid%144;
    int tr0 = (tile/12)*16, tc0 = (tile%12)*16;
    __shared__ __align__(16) unsigned short z_lds[324*64];     // 41472 B
    __shared__ float ssc[64], sbi[64], sbias[64];
    int tid = threadIdx.x;
    if(tid<64){
        int c=tid, g=n*4+(c>>4);
        float cnt=16.f*(float)HW;
        float m=st[g*32]/cnt, var=st[g*32+1]/cnt-m*m;
        float sc=gng[c]*rsqrtf(var+1e-5f);
        ssc[c]=sc; sbi[c]=gnb[c]-m*sc;
        sbias[c]=hb[c];
    }
    __syncthreads();
    const uint4* hpm = (const uint4*)(high + (size_t)n*HW*64);
    for(int e=tid;e<2592;e+=256){
        int hpx = e>>3, q = e&7;
        int hr = hpx/18, hc = hpx - hr*18;
        int gr = tr0+hr-1, gc = tc0+hc-1;
        uint4 w; w.x=0; w.y=0; w.z=0; w.w=0;
        if(gr>=0 && gr<Hh && gc>=0 && gc<Ww){
            uint4 v = hpm[(size_t)(gr*Ww+gc)*8 + q];
            unsigned int vv[4]={v.x,v.y,v.z,v.w};
            #pragma unroll
            for(int j=0;j<4;j++){
                int c = q*8 + 2*j;
                float f0 = bf2f(vv[j]&0xffffu)*ssc[c]   + sbi[c];
                float f1 = bf2f(vv[j]>>16)   *ssc[c+1] + sbi[c+1];
                f0 = f0>=0.f ? f0 : 0.01f*f0;
                f1 = f1>=0.f ? f1 : 0.01f*f1;
                vv[j] = (unsigned int)f2bf(f0) | ((unsigned int)f2bf(f1)<<16);
            }
            w.x=vv[0]; w.y=vv[1]; w.z=vv[2]; w.w=vv[3];
        }
        *(uint4*)&z_lds[hpx*64 + ((q*8) ^ ((hpx&7)<<3))] = w;
    }
    __syncthreads();
    int wv = tid>>6, ln = tid&63;
    int col = ln&15, kq = ln>>4;
    f32x4 acc[4][4];                            // [og][rf]
    #pragma unroll
    for(int og=0;og<4;og++)
        #pragma unroll
        for(int rf=0;rf<4;rf++) acc[og][rf]=(f32x4){0.f,0.f,0.f,0.f};
    #pragma unroll
    for(int t=0;t<9;t++){
        int dr = t/3 - 1, dc = t%3 - 1;
        #pragma unroll
        for(int kb=0;kb<2;kb++){
            int k0 = kb*32 + kq*8;
            s16x8 afr[4];
            #pragma unroll
            for(int og=0;og<4;og++)
                afr[og] = *(const s16x8*)&g_wt[(size_t)(((og*9+t)*16+col)*64) + k0];
            #pragma unroll
            for(int rf=0;rf<4;rf++){
                int r = wv*4 + rf;
                int hpx = (r+1+dr)*18 + (col+1+dc);
                const s16x8 bfr = *(const s16x8*)&z_lds[hpx*64 + (k0 ^ ((hpx&7)<<3))];
                #pragma unroll
                for(int og=0;og<4;og++)
                    acc[og][rf] = __builtin_amdgcn_mfma_f32_16x16x32_bf16(afr[og], bfr, acc[og][rf], 0, 0, 0);
            }
        }
    }
    const unsigned short* hres = high + (size_t)n*HW*64;
    #pragma unroll
    for(int rf=0;rf<4;rf++){
        int r = wv*4 + rf;
        int gpx = (tr0+r)*Ww + (tc0+col);
        #pragma unroll
        for(int og=0;og<4;og++){
            US4 rv = *(const US4*)&hres[(size_t)gpx*64 + og*16 + kq*4];
            float rvf[4] = {bf2f(rv.x), bf2f(rv.y), bf2f(rv.z), bf2f(rv.w)};
            unsigned short tmp[4];
            #pragma unroll
            for(int reg=0;reg<4;reg++){
                int oc = og*16 + kq*4 + reg;
                tmp[reg] = f2bf(acc[og][rf][reg] + sbias[oc] + rvf[reg]);
            }
            US4 pk; pk.x=tmp[0]; pk.y=tmp[1]; pk.z=tmp[2]; pk.w=tmp[3];
            *(US4*)&enh_high[((size_t)n*HW + gpx)*64 + og*16 + kq*4] = pk;
        }
    }
}

// ---------------- kernel 9: fusion conv1x1 128->128 via MFMA + per-block stat partials ----------------
__global__ void __launch_bounds__(256,2)
k_fu1m(const unsigned short* __restrict__ el, const unsigned short* __restrict__ eh,
       const unsigned short* __restrict__ wA, const float* __restrict__ b,
       unsigned short* __restrict__ o1, float* __restrict__ partial){
    int bid = blockIdx.x;
    int n = bid/288, pt = bid%288;
    int px0 = pt*128;
    __shared__ __align__(16) unsigned short sA[128*128];   // 32 KB
    __shared__ __align__(16) unsigned short sB[128*128];   // 32 KB
    __shared__ float sb[128];
    __shared__ float redsm[16];
    int tid = threadIdx.x;
    {
        const uint4* s=(const uint4*)wA; uint4* d=(uint4*)sA;
        for(int i=tid;i<2048;i+=256) d[i]=s[i];
    }
    if(tid<128) sb[tid]=b[tid];
    {
        const uint4* se=(const uint4*)(el + ((size_t)n*HW+px0)*64);
        const uint4* sh=(const uint4*)(eh + ((size_t)n*HW+px0)*64);
        for(int i=tid;i<2048;i+=256){
            int px=i>>4, q=i&15;
            uint4 v = (q<8)? se[px*8+q] : sh[px*8+(q-8)];
            int c0 = q*8;
            *(uint4*)&sB[px*128 + (c0 ^ ((px&15)<<3))] = v;
        }
    }
    __syncthreads();
    int wv=tid>>6, ln=tid&63;
    int wm=wv>>1, wn=wv&1;
    int col=ln&15, kq=ln>>4;
    f32x4 acc[4][4];
    #pragma unroll
    for(int m=0;m<4;m++)
        #pragma unroll
        for(int nf=0;nf<4;nf++) acc[m][nf]=(f32x4){0.f,0.f,0.f,0.f};
    #pragma unroll
    for(int kb=0;kb<4;kb++){
        int k0 = kb*32 + kq*8;
        s16x8 a[4], bf[4];
        #pragma unroll
        for(int m=0;m<4;m++)
            a[m] = *(const s16x8*)&sA[(wm*64+m*16+col)*128 + (k0 ^ (col<<3))];
        #pragma unroll
        for(int nf=0;nf<4;nf++)
            bf[nf] = *(const s16x8*)&sB[(wn*64+nf*16+col)*128 + (k0 ^ (col<<3))];
        #pragma unroll
        for(int m=0;m<4;m++)
            #pragma unroll
            for(int nf=0;nf<4;nf++)
                acc[m][nf] = __builtin_amdgcn_mfma_f32_16x16x32_bf16(a[m], bf[nf], acc[m][nf], 0,0,0);
    }
    float sg0=0.f,sq0=0.f,sg1=0.f,sq1=0.f;
    #pragma unroll
    for(int m=0;m<4;m++){
        int oc0 = wm*64 + m*16 + kq*4;
        #pragma unroll
        for(int nf=0;nf<4;nf++){
            int px = wn*64 + nf*16 + col;
            unsigned short tmp[4];
            #pragma unroll
            for(int reg=0;reg<4;reg++){
                float v = acc[m][nf][reg] + sb[oc0+reg];
                if(m<2){ sg0+=v; sq0+=v*v; } else { sg1+=v; sq1+=v*v; }
                tmp[reg]=f2bf(v);
            }
            US4 pk; pk.x=tmp[0]; pk.y=tmp[1]; pk.z=tmp[2]; pk.w=tmp[3];
            *(US4*)&o1[((size_t)n*HW + px0 + px)*128 + oc0] = pk;
        }
    }
    #pragma unroll
    for(int o=32;o>0;o>>=1){
        sg0+=__shfl_down(sg0,o); sq0+=__shfl_down(sq0,o);
        sg1+=__shfl_down(sg1,o); sq1+=__shfl_down(sq1,o);
    }
    if(ln==0){ redsm[wv*4+0]=sg0; redsm[wv*4+1]=sq0; redsm[wv*4+2]=sg1; redsm[wv*4+3]=sq1; }
    __syncthreads();
    if(tid<8){
        int gl = tid>>1, comp = tid&1;
        int wbase = (gl>>1)*2;
        int off = (gl&1)*2 + comp;
        partial[(size_t)bid*8 + tid] = redsm[wbase*4+off] + redsm[(wbase+1)*4+off];
    }
}

// ---------------- kernel 10: GN + GELU + conv1x1 128->64 via MFMA -> out(f32) ----------------
__global__ void __launch_bounds__(256,2)
k_fu2m(const unsigned short* __restrict__ o1, const float* __restrict__ st,
       const float* __restrict__ gg, const float* __restrict__ gb,
       const unsigned short* __restrict__ wA, const float* __restrict__ b2,
       float* __restrict__ out){
    int bid = blockIdx.x;
    int n = bid/288, pt = bid%288;
    int px0 = pt*128;
    __shared__ __align__(16) unsigned short sA[64*128];    // 16 KB
    __shared__ __align__(16) unsigned short sB[128*128];   // 32 KB
    __shared__ float ssc[128], sbi[128], sb2[64];
    int tid = threadIdx.x;
    {
        const uint4* s=(const uint4*)wA; uint4* d=(uint4*)sA;
        for(int i=tid;i<1024;i+=256) d[i]=s[i];
    }
    if(tid<128){
        int c=tid, g=n*4+(c>>5);
        float cnt = 32.f*(float)HW;
        float m = st[g*32]/cnt;
        float var = st[g*32+1]/cnt - m*m;
        float sc = gg[c]*rsqrtf(var+1e-5f);
        ssc[c]=sc; sbi[c]=gb[c]-m*sc;
    }
    if(tid<64) sb2[tid]=b2[tid];
    __syncthreads();
    {
        const uint4* so=(const uint4*)(o1 + ((size_t)n*HW+px0)*128);
        for(int i=tid;i<2048;i+=256){
            int px=i>>4, q=i&15;
            int c0 = q*8;
            uint4 v = so[px*16+q];
            unsigned int vals[4] = {v.x,v.y,v.z,v.w};
            #pragma unroll
            for(int j=0;j<4;j++){
                int c = c0 + 2*j;
                float f0 = bf2f(vals[j]&0xffffu)*ssc[c]   + sbi[c];
                float f1 = bf2f(vals[j]>>16)   *ssc[c+1] + sbi[c+1];
                f0 = 0.5f*f0*(1.f+erff(f0*0.70710678118654752f));
                f1 = 0.5f*f1*(1.f+erff(f1*0.70710678118654752f));
                vals[j] = (unsigned int)f2bf(f0) | ((unsigned int)f2bf(f1)<<16);
            }
            uint4 w; w.x=vals[0]; w.y=vals[1]; w.z=vals[2]; w.w=vals[3];
            *(uint4*)&sB[px*128 + (c0 ^ ((px&15)<<3))] = w;
        }
    }
    __syncthreads();
    int wv=tid>>6, ln=tid&63;
    int col=ln&15, kq=ln>>4;
    f32x4 acc[4][2];
    #pragma unroll
    for(int m=0;m<4;m++){ acc[m][0]=(f32x4){0,0,0,0}; acc[m][1]=(f32x4){0,0,0,0}; }
    #pragma unroll
    for(int kb=0;kb<4;kb++){
        int k0 = kb*32 + kq*8;
        s16x8 a[4], bf[2];
        #pragma unroll
        for(int m=0;m<4;m++)
            a[m] = *(const s16x8*)&sA[(m*16+col)*128 + (k0 ^ (col<<3))];
        #pragma unroll
        for(int nf=0;nf<2;nf++)
            bf[nf] = *(const s16x8*)&sB[(wv*32+nf*16+col)*128 + (k0 ^ (col<<3))];
        #pragma unroll
        for(int m=0;m<4;m++)
            #pragma unroll
            for(int nf=0;nf<2;nf++)
                acc[m][nf] = __builtin_amdgcn_mfma_f32_16x16x32_bf16(a[m], bf[nf], acc[m][nf], 0,0,0);
    }
    #pragma unroll
    for(int m=0;m<4;m++){
        int oc0 = m*16 + kq*4;
        #pragma unroll
        for(int nf=0;nf<2;nf++){
            int px = px0 + wv*32 + nf*16 + col;
            #pragma unroll
            for(int reg=0;reg<4;reg++){
                int oc = oc0+reg;
                out[((size_t)n*64+oc)*HW + px] = acc[m][nf][reg] + sb2[oc];
            }
        }
    }
}

extern "C" void kernel_launch(void* const* d_in, const int* in_sizes, int n_in,
                              void* d_out, int out_size, void* d_ws, size_t ws_size,
                              hipStream_t stream) {
    const float* x        = (const float*)d_in[0];
    const float* w_filter = (const float*)d_in[1];
    const float* gnf_g    = (const float*)d_in[2];
    const float* gnf_b    = (const float*)d_in[3];
    const float* lb_w1    = (const float*)d_in[4];
    const float* lb_b1    = (const float*)d_in[5];
    const float* lb_a1    = (const float*)d_in[6];
    const float* lb_dw1   = (const float*)d_in[7];
    const float* lb_db1   = (const float*)d_in[8];
    const float* lb_w2    = (const float*)d_in[9];
    const float* lb_b2    = (const float*)d_in[10];
    const float* lb_a2    = (const float*)d_in[11];
    const float* lb_dw2   = (const float*)d_in[12];
    const float* lb_db2   = (const float*)d_in[13];
    const float* lb_w3    = (const float*)d_in[14];
    const float* lb_b3    = (const float*)d_in[15];
    const float* lb_a3    = (const float*)d_in[16];
    const float* lb_dw3   = (const float*)d_in[17];
    const float* lb_db3   = (const float*)d_in[18];
    const float* lb_w4    = (const float*)d_in[19];
    const float* lb_b4    = (const float*)d_in[20];
    const float* lb_a4    = (const float*)d_in[21];
    const float* lb_w5    = (const float*)d_in[22];
    const float* lb_b5    = (const float*)d_in[23];
    const float* hb_gn_g  = (const float*)d_in[24];
    const float* hb_gn_b  = (const float*)d_in[25];
    const float* hb_w     = (const float*)d_in[26];
    const float* hb_b     = (const float*)d_in[27];
    const float* fu_w1    = (const float*)d_in[28];
    const float* fu_b1    = (const float*)d_in[29];
    const float* fu_gn_g  = (const float*)d_in[30];
    const float* fu_gn_b  = (const float*)d_in[31];
    const float* fu_w2    = (const float*)d_in[32];
    const float* fu_b2    = (const float*)d_in[33];
    float* out = (float*)d_out;

    // ws layout (bytes)
    const size_t O1B = (size_t)Nn*HW*128*2;     // 37,748,736  o1 bf16 [n][px][128]
    const size_t EB  = (size_t)Nn*HW*64*2;      // 18,874,368  bf16 [n][px][64]
    const size_t YB  = (size_t)Nn*16*HW*4;      // 9,437,184   f32 planar
    char* Wb = (char*)d_ws;
    unsigned short* o1       = (unsigned short*)Wb;               // [0, O1B)
    unsigned short* high     = (unsigned short*)Wb;               // aliases o1 (dead before fu1m writes)
    unsigned short* enh_low  = (unsigned short*)(Wb + O1B);
    unsigned short* enh_high = (unsigned short*)(Wb + O1B + EB);
    float* y1                = (float*)(Wb + O1B + 2*EB);
    float* y2                = (float*)(Wb + O1B + 2*EB + YB);
    unsigned short* g_wt     = (unsigned short*)(Wb + O1B + 2*EB + 2*YB); // 36864 ush
    unsigned short* g_wfu1   = g_wt + 36864;                              // 16384 ush
    unsigned short* g_wfu2   = g_wfu1 + 16384;                            // 8192 ush
    float* fp      = (float*)(g_wfu2 + 8192);
    float* fsm     = fp + 256;
    float* st_hb   = fsm + 2304;       // 16 groups * 32 floats (padded lines)
    float* st_o1   = st_hb + 512;      // 16 groups * 32 floats
    float* part_hb = st_o1 + 512;      // 576 * 8 floats
    float* part_o1 = part_hb + 4608;   // 1152 * 8 floats
    unsigned short* xbf = (unsigned short*)(part_o1 + 9216);              // bf16 [n][px][64]

    k_xprep<<<Nn*144, 256, 0, stream>>>(x, xbf);
    k_prep<<<496, 256, 0, stream>>>(hb_w, fu_w1, fu_w2, x, g_wt, g_wfu1, g_wfu2, fp);
    k_filter<<<Nn, 576, 0, stream>>>(fp, w_filter, gnf_g, gnf_b, fsm);
    k_lowhigh<<<Nn*144, 256, 0, stream>>>(xbf, fsm, lb_w1, lb_b1, lb_a1, high, y1, part_hb);
    k_redstats<<<16, 256, 0, stream>>>(part_hb, st_hb, 144);
    k_conv3m<<<Nn*144, 256, 0, stream>>>(high, st_hb, hb_gn_g, hb_gn_b, g_wt, hb_b, enh_high);
    k_dw_c<5><<<Nn*PIXBLK, 256, 0, stream>>>(y1, lb_dw1, lb_db1, lb_w2, lb_b2, lb_a2, y2);
    k_dw_c<1><<<Nn*PIXBLK, 256, 0, stream>>>(y2, lb_dw2, lb_db2, lb_w3, lb_b3, lb_a3, y1);
    k_dw3_final<<<Nn*PIXBLK, 256, 0, stream>>>(y1, lb_dw3, lb_db3, lb_w4, lb_b4, lb_a4,
                                               lb_w5, lb_b5, enh_low);
    k_fu1m<<<Nn*288, 256, 0, stream>>>(enh_low, enh_high, g_wfu1, fu_b1, o1, part_o1);
    k_redstats<<<16, 256, 0, stream>>>(part_o1, st_o1, 288);
    k_fu2m<<<Nn*288, 256, 0, stream>>>(o1, st_o1, fu_gn_g, fu_gn_b, g_wfu2, fu_b2, out);
}